// Round 1
// baseline (867.620 us; speedup 1.0000x reference)
//
#include <hip/hip_runtime.h>
#include <math.h>

#define LRELU 0.2f

// ---------------- CSR build ----------------

__global__ void k_hist(const int* __restrict__ dst, int E, int* __restrict__ deg) {
    int i = blockIdx.x * blockDim.x + threadIdx.x;
    int stride = gridDim.x * blockDim.x;
    for (; i < E; i += stride) atomicAdd(&deg[dst[i]], 1);
}

// Single-block exclusive scan: 1024 threads, each owns a contiguous chunk.
__global__ __launch_bounds__(1024) void k_scan(const int* __restrict__ deg, int N,
                                               int* __restrict__ rowptr,
                                               int* __restrict__ cursor) {
    const int T = 1024;
    int tid = threadIdx.x;
    int seq = (N + T - 1) / T;
    int begin = tid * seq; if (begin > N) begin = N;
    int end = begin + seq; if (end > N) end = N;

    int sum = 0;
    for (int i = begin; i < end; ++i) sum += deg[i];

    int lane = tid & 63, wv = tid >> 6;
    int v = sum;
#pragma unroll
    for (int off = 1; off < 64; off <<= 1) {
        int t = __shfl_up(v, off, 64);
        if (lane >= off) v += t;
    }
    __shared__ int wsum[16];
    if (lane == 63) wsum[wv] = v;
    __syncthreads();
    if (wv == 0) {
        int w = (lane < 16) ? wsum[lane] : 0;
#pragma unroll
        for (int off = 1; off < 16; off <<= 1) {
            int t = __shfl_up(w, off, 64);
            if (lane >= off) w += t;
        }
        if (lane < 16) wsum[lane] = w;
    }
    __syncthreads();
    int waveoff = (wv > 0) ? wsum[wv - 1] : 0;
    int run = waveoff + (v - sum);   // exclusive prefix for this thread
    for (int i = begin; i < end; ++i) {
        rowptr[i] = run;
        cursor[i] = run;
        run += deg[i];
    }
    if (tid == T - 1) rowptr[N] = run;   // == E
}

__global__ void k_scatter(const int* __restrict__ src, const int* __restrict__ dst,
                          int E, int* __restrict__ cursor, int* __restrict__ col) {
    int i = blockIdx.x * blockDim.x + threadIdx.x;
    int stride = gridDim.x * blockDim.x;
    for (; i < E; i += stride) {
        int d = dst[i];
        int p = atomicAdd(&cursor[d], 1);
        col[p] = src[i];
    }
}

// ---------------- GEMM + attention projections ----------------
// Layer 1: X[N,256] @ W[256,64] -> H[N,64]; a_src/a_dst per (node, head=8).
// One wave per 8 rows; lane = output channel (hc = h*8+c).
__global__ __launch_bounds__(256) void k_gemm1(const float* __restrict__ X,
                                               const float* __restrict__ W,
                                               const float* __restrict__ atts,
                                               const float* __restrict__ attd,
                                               int N, float* __restrict__ H,
                                               float* __restrict__ asrc,
                                               float* __restrict__ adst) {
    int lane = threadIdx.x & 63;
    int wave = (blockIdx.x << 2) + (threadIdx.x >> 6);
    int r0 = wave * 8;
    if (r0 >= N) return;
    int rmax = N - r0; if (rmax > 8) rmax = 8;

    float acc[8] = {0.f, 0.f, 0.f, 0.f, 0.f, 0.f, 0.f, 0.f};
    for (int k = 0; k < 256; k += 4) {
        float w0 = W[(k + 0) * 64 + lane];
        float w1 = W[(k + 1) * 64 + lane];
        float w2 = W[(k + 2) * 64 + lane];
        float w3 = W[(k + 3) * 64 + lane];
#pragma unroll
        for (int r = 0; r < 8; r++) {
            if (r < rmax) {
                float4 xv = *reinterpret_cast<const float4*>(X + (size_t)(r0 + r) * 256 + k);
                acc[r] = fmaf(xv.x, w0, acc[r]);
                acc[r] = fmaf(xv.y, w1, acc[r]);
                acc[r] = fmaf(xv.z, w2, acc[r]);
                acc[r] = fmaf(xv.w, w3, acc[r]);
            }
        }
    }
    float avs = atts[lane], avd = attd[lane];
#pragma unroll
    for (int r = 0; r < 8; r++) {
        if (r < rmax) {
            int row = r0 + r;
            H[(size_t)row * 64 + lane] = acc[r];
            float vs = acc[r] * avs, vd = acc[r] * avd;
            vs += __shfl_xor(vs, 1, 64); vs += __shfl_xor(vs, 2, 64); vs += __shfl_xor(vs, 4, 64);
            vd += __shfl_xor(vd, 1, 64); vd += __shfl_xor(vd, 2, 64); vd += __shfl_xor(vd, 4, 64);
            if ((lane & 7) == 0) {
                asrc[row * 8 + (lane >> 3)] = vs;
                adst[row * 8 + (lane >> 3)] = vd;
            }
        }
    }
}

// Layer 2: X[N,64] @ W[64,64] -> G[N,64]; single-head a_src/a_dst per node.
__global__ __launch_bounds__(256) void k_gemm2(const float* __restrict__ X,
                                               const float* __restrict__ W,
                                               const float* __restrict__ atts,
                                               const float* __restrict__ attd,
                                               int N, float* __restrict__ G,
                                               float* __restrict__ asrc,
                                               float* __restrict__ adst) {
    int lane = threadIdx.x & 63;
    int wave = (blockIdx.x << 2) + (threadIdx.x >> 6);
    int r0 = wave * 8;
    if (r0 >= N) return;
    int rmax = N - r0; if (rmax > 8) rmax = 8;

    float acc[8] = {0.f, 0.f, 0.f, 0.f, 0.f, 0.f, 0.f, 0.f};
    for (int k = 0; k < 64; k += 4) {
        float w0 = W[(k + 0) * 64 + lane];
        float w1 = W[(k + 1) * 64 + lane];
        float w2 = W[(k + 2) * 64 + lane];
        float w3 = W[(k + 3) * 64 + lane];
#pragma unroll
        for (int r = 0; r < 8; r++) {
            if (r < rmax) {
                float4 xv = *reinterpret_cast<const float4*>(X + (size_t)(r0 + r) * 64 + k);
                acc[r] = fmaf(xv.x, w0, acc[r]);
                acc[r] = fmaf(xv.y, w1, acc[r]);
                acc[r] = fmaf(xv.z, w2, acc[r]);
                acc[r] = fmaf(xv.w, w3, acc[r]);
            }
        }
    }
    float avs = atts[lane], avd = attd[lane];
#pragma unroll
    for (int r = 0; r < 8; r++) {
        if (r < rmax) {
            int row = r0 + r;
            G[(size_t)row * 64 + lane] = acc[r];
            float vs = acc[r] * avs, vd = acc[r] * avd;
#pragma unroll
            for (int off = 1; off < 64; off <<= 1) {
                vs += __shfl_xor(vs, off, 64);
                vd += __shfl_xor(vd, off, 64);
            }
            if (lane == 0) { asrc[row] = vs; adst[row] = vd; }
        }
    }
}

// ---------------- Fused per-dst gather (softmax + aggregate) ----------------
// Layer 1: one wave per dst node; lane = hc channel (head = lane>>3).
// out = ELU( (sum_j w_j * H[src_j]) / (sum_j w_j + 1e-16) + bias )
__global__ __launch_bounds__(256) void k_gather1(const int* __restrict__ rowptr,
                                                 const int* __restrict__ col,
                                                 const float* __restrict__ H,
                                                 const float* __restrict__ asrc,
                                                 const float* __restrict__ adst,
                                                 const float* __restrict__ bias,
                                                 int N, float* __restrict__ out) {
    int lane = threadIdx.x & 63;
    int d = (blockIdx.x << 2) + (threadIdx.x >> 6);
    if (d >= N) return;
    int h = lane >> 3;
    float adv = adst[d * 8 + h];
    int jb = rowptr[d], je = rowptr[d + 1];
    float acc = 0.f, denom = 0.f;
    for (int j = jb; j < je; ++j) {
        int s = col[j];
        float e = asrc[s * 8 + h] + adv;
        e = (e > 0.f) ? e : LRELU * e;
        float w = __expf(e);
        denom += w;
        acc = fmaf(w, H[(size_t)s * 64 + lane], acc);
    }
    float v = acc / (denom + 1e-16f) + bias[lane];
    out[(size_t)d * 64 + lane] = (v > 0.f) ? v : expm1f(v);   // ELU(alpha=1)
}

// Layer 2 (single head) + bias + log_softmax over the 64 channels.
__global__ __launch_bounds__(256) void k_gather2(const int* __restrict__ rowptr,
                                                 const int* __restrict__ col,
                                                 const float* __restrict__ G,
                                                 const float* __restrict__ asrc,
                                                 const float* __restrict__ adst,
                                                 const float* __restrict__ bias,
                                                 int N, float* __restrict__ out) {
    int lane = threadIdx.x & 63;
    int d = (blockIdx.x << 2) + (threadIdx.x >> 6);
    if (d >= N) return;
    float adv = adst[d];
    int jb = rowptr[d], je = rowptr[d + 1];
    float acc = 0.f, denom = 0.f;
    for (int j = jb; j < je; ++j) {
        int s = col[j];
        float e = asrc[s] + adv;
        e = (e > 0.f) ? e : LRELU * e;
        float w = __expf(e);
        denom += w;
        acc = fmaf(w, G[(size_t)s * 64 + lane], acc);
    }
    float v = acc / (denom + 1e-16f) + bias[lane];
    // log_softmax across the wave (64 lanes = 64 classes)
    float m = v;
#pragma unroll
    for (int off = 1; off < 64; off <<= 1) m = fmaxf(m, __shfl_xor(m, off, 64));
    float ex = __expf(v - m);
    float ssum = ex;
#pragma unroll
    for (int off = 1; off < 64; off <<= 1) ssum += __shfl_xor(ssum, off, 64);
    out[(size_t)d * 64 + lane] = v - m - __logf(ssum);
}

// ---------------- launch ----------------

extern "C" void kernel_launch(void* const* d_in, const int* in_sizes, int n_in,
                              void* d_out, int out_size, void* d_ws, size_t ws_size,
                              hipStream_t stream) {
    const float* x   = (const float*)d_in[0];
    const int*   ei  = (const int*)d_in[1];
    const float* W1  = (const float*)d_in[2];
    const float* as1 = (const float*)d_in[3];
    const float* ad1 = (const float*)d_in[4];
    const float* b1  = (const float*)d_in[5];
    const float* W2  = (const float*)d_in[6];
    const float* as2 = (const float*)d_in[7];
    const float* ad2 = (const float*)d_in[8];
    const float* b2  = (const float*)d_in[9];
    float* out = (float*)d_out;

    const int N = in_sizes[0] / 256;
    const int E = in_sizes[1] / 2;
    const int* src = ei;
    const int* dst = ei + E;

    char* ws = (char*)d_ws;
    size_t off = 0;
    auto alloc = [&](size_t bytes) -> void* {
        void* p = ws + off;
        off = (off + bytes + 255) & ~(size_t)255;
        return p;
    };
    int*   deg    = (int*)alloc((size_t)N * 4);
    int*   rowptr = (int*)alloc((size_t)(N + 1) * 4);
    int*   cursor = (int*)alloc((size_t)N * 4);
    int*   col    = (int*)alloc((size_t)E * 4);
    float* h1     = (float*)alloc((size_t)N * 64 * 4);
    float* a_s1   = (float*)alloc((size_t)N * 8 * 4);
    float* a_d1   = (float*)alloc((size_t)N * 8 * 4);
    float* h2     = (float*)alloc((size_t)N * 64 * 4);
    float* g      = (float*)alloc((size_t)N * 64 * 4);
    float* a_s2   = (float*)alloc((size_t)N * 4);
    float* a_d2   = (float*)alloc((size_t)N * 4);
    (void)ws_size; (void)n_in; (void)out_size;

    hipMemsetAsync(deg, 0, (size_t)N * 4, stream);
    k_hist<<<2048, 256, 0, stream>>>(dst, E, deg);
    k_scan<<<1, 1024, 0, stream>>>(deg, N, rowptr, cursor);
    k_scatter<<<2048, 256, 0, stream>>>(src, dst, E, cursor, col);

    int waves = (N + 7) / 8;
    int gemm_blocks = (waves + 3) / 4;
    k_gemm1<<<gemm_blocks, 256, 0, stream>>>(x, W1, as1, ad1, N, h1, a_s1, a_d1);

    int gather_blocks = (N + 3) / 4;
    k_gather1<<<gather_blocks, 256, 0, stream>>>(rowptr, col, h1, a_s1, a_d1, b1, N, h2);

    k_gemm2<<<gemm_blocks, 256, 0, stream>>>(h2, W2, as2, ad2, N, g, a_s2, a_d2);

    k_gather2<<<gather_blocks, 256, 0, stream>>>(rowptr, col, g, a_s2, a_d2, b2, N, out);
}

// Round 2
// 754.255 us; speedup vs baseline: 1.1503x; 1.1503x over previous
//
#include <hip/hip_runtime.h>
#include <math.h>

#define LRELU 0.2f

static __device__ __forceinline__ float bf2f(unsigned short u) {
    union { unsigned int i; float f; } c; c.i = ((unsigned int)u) << 16; return c.f;
}
static __device__ __forceinline__ unsigned short f2bf(float f) {
    union { float f; unsigned int i; } c; c.f = f;
    unsigned int x = c.i;
    return (unsigned short)((x + 0x7fffu + ((x >> 16) & 1u)) >> 16);  // RNE
}

// ---------------- CSR build ----------------

__global__ void k_hist(const int* __restrict__ dst, int E, int* __restrict__ deg) {
    int i = blockIdx.x * blockDim.x + threadIdx.x;
    int stride = gridDim.x * blockDim.x;
    for (; i < E; i += stride) atomicAdd(&deg[dst[i]], 1);
}

// 1024 elements per block, 256 threads x 4 elems. Partial sums.
__global__ __launch_bounds__(256) void k_partsum(const int* __restrict__ deg, int N,
                                                 int* __restrict__ bsum) {
    int t = threadIdx.x, lane = t & 63, wv = t >> 6;
    int base = blockIdx.x * 1024 + t * 4;
    int s = 0;
    if (base + 3 < N) {
        int4 v = *reinterpret_cast<const int4*>(deg + base);
        s = v.x + v.y + v.z + v.w;
    } else {
        for (int i = 0; i < 4; ++i) if (base + i < N) s += deg[base + i];
    }
#pragma unroll
    for (int off = 1; off < 64; off <<= 1) s += __shfl_xor(s, off, 64);
    __shared__ int ws[4];
    if (lane == 0) ws[wv] = s;
    __syncthreads();
    if (t == 0) bsum[blockIdx.x] = ws[0] + ws[1] + ws[2] + ws[3];
}

// Single wave scans block sums -> exclusive block offsets; writes rowptr[N].
__global__ __launch_bounds__(64) void k_scansum(const int* __restrict__ bsum, int nb,
                                                int* __restrict__ boff,
                                                int* __restrict__ rowptr, int N) {
    int lane = threadIdx.x;
    int run = 0;
    for (int base = 0; base < nb; base += 64) {
        int v = (base + lane < nb) ? bsum[base + lane] : 0;
        int inc = v;
#pragma unroll
        for (int off = 1; off < 64; off <<= 1) {
            int t = __shfl_up(inc, off, 64);
            if (lane >= off) inc += t;
        }
        if (base + lane < nb) boff[base + lane] = run + inc - v;
        run += __shfl(inc, 63, 64);
    }
    if (lane == 0) rowptr[N] = run;
}

// Block-local scan + write rowptr/cursor.
__global__ __launch_bounds__(256) void k_scanwrite(const int* __restrict__ deg, int N,
                                                   const int* __restrict__ boff,
                                                   int* __restrict__ rowptr,
                                                   int* __restrict__ cursor) {
    int t = threadIdx.x, lane = t & 63, wv = t >> 6;
    int base = blockIdx.x * 1024 + t * 4;
    int v[4] = {0, 0, 0, 0};
    if (base + 3 < N) {
        int4 q = *reinterpret_cast<const int4*>(deg + base);
        v[0] = q.x; v[1] = q.y; v[2] = q.z; v[3] = q.w;
    } else {
        for (int i = 0; i < 4; ++i) if (base + i < N) v[i] = deg[base + i];
    }
    int s = v[0] + v[1] + v[2] + v[3];
    int inc = s;
#pragma unroll
    for (int off = 1; off < 64; off <<= 1) {
        int q = __shfl_up(inc, off, 64);
        if (lane >= off) inc += q;
    }
    __shared__ int wtot[4];
    if (lane == 63) wtot[wv] = inc;
    __syncthreads();
    int woff = 0;
    for (int w = 0; w < wv; ++w) woff += wtot[w];
    int excl = woff + inc - s + boff[blockIdx.x];
    for (int i = 0; i < 4; ++i) {
        if (base + i < N) {
            rowptr[base + i] = excl;
            cursor[base + i] = excl;
            excl += v[i];
        }
    }
}

__global__ void k_scatter(const int* __restrict__ src, const int* __restrict__ dst,
                          int E, int* __restrict__ cursor, int* __restrict__ col) {
    int i = blockIdx.x * blockDim.x + threadIdx.x;
    int stride = gridDim.x * blockDim.x;
    for (; i < E; i += stride) {
        int d = dst[i];
        int p = atomicAdd(&cursor[d], 1);
        col[p] = src[i];
    }
}

// ---------------- GEMM + attention projections ----------------
// Layer 1: X[N,256] @ W[256,64] -> Hb[N,64] (bf16); a_src/a_dst per (node, head).
__global__ __launch_bounds__(256) void k_gemm1(const float* __restrict__ X,
                                               const float* __restrict__ W,
                                               const float* __restrict__ atts,
                                               const float* __restrict__ attd,
                                               int N, unsigned short* __restrict__ Hb,
                                               float* __restrict__ asrc,
                                               float* __restrict__ adst) {
    int lane = threadIdx.x & 63;
    int wave = (blockIdx.x << 2) + (threadIdx.x >> 6);
    int r0 = wave * 8;
    if (r0 >= N) return;
    int rmax = N - r0; if (rmax > 8) rmax = 8;

    float acc[8] = {0.f, 0.f, 0.f, 0.f, 0.f, 0.f, 0.f, 0.f};
    for (int k = 0; k < 256; k += 4) {
        float w0 = W[(k + 0) * 64 + lane];
        float w1 = W[(k + 1) * 64 + lane];
        float w2 = W[(k + 2) * 64 + lane];
        float w3 = W[(k + 3) * 64 + lane];
#pragma unroll
        for (int r = 0; r < 8; r++) {
            if (r < rmax) {
                float4 xv = *reinterpret_cast<const float4*>(X + (size_t)(r0 + r) * 256 + k);
                acc[r] = fmaf(xv.x, w0, acc[r]);
                acc[r] = fmaf(xv.y, w1, acc[r]);
                acc[r] = fmaf(xv.z, w2, acc[r]);
                acc[r] = fmaf(xv.w, w3, acc[r]);
            }
        }
    }
    float avs = atts[lane], avd = attd[lane];
#pragma unroll
    for (int r = 0; r < 8; r++) {
        if (r < rmax) {
            int row = r0 + r;
            Hb[(size_t)row * 64 + lane] = f2bf(acc[r]);
            float vs = acc[r] * avs, vd = acc[r] * avd;
            vs += __shfl_xor(vs, 1, 64); vs += __shfl_xor(vs, 2, 64); vs += __shfl_xor(vs, 4, 64);
            vd += __shfl_xor(vd, 1, 64); vd += __shfl_xor(vd, 2, 64); vd += __shfl_xor(vd, 4, 64);
            if ((lane & 7) == 0) {
                asrc[row * 8 + (lane >> 3)] = vs;
                adst[row * 8 + (lane >> 3)] = vd;
            }
        }
    }
}

// Layer 2: X[N,64] @ W[64,64] -> Gb[N,64] (bf16); single-head a_src/a_dst per node.
__global__ __launch_bounds__(256) void k_gemm2(const float* __restrict__ X,
                                               const float* __restrict__ W,
                                               const float* __restrict__ atts,
                                               const float* __restrict__ attd,
                                               int N, unsigned short* __restrict__ Gb,
                                               float* __restrict__ asrc,
                                               float* __restrict__ adst) {
    int lane = threadIdx.x & 63;
    int wave = (blockIdx.x << 2) + (threadIdx.x >> 6);
    int r0 = wave * 8;
    if (r0 >= N) return;
    int rmax = N - r0; if (rmax > 8) rmax = 8;

    float acc[8] = {0.f, 0.f, 0.f, 0.f, 0.f, 0.f, 0.f, 0.f};
    for (int k = 0; k < 64; k += 4) {
        float w0 = W[(k + 0) * 64 + lane];
        float w1 = W[(k + 1) * 64 + lane];
        float w2 = W[(k + 2) * 64 + lane];
        float w3 = W[(k + 3) * 64 + lane];
#pragma unroll
        for (int r = 0; r < 8; r++) {
            if (r < rmax) {
                float4 xv = *reinterpret_cast<const float4*>(X + (size_t)(r0 + r) * 64 + k);
                acc[r] = fmaf(xv.x, w0, acc[r]);
                acc[r] = fmaf(xv.y, w1, acc[r]);
                acc[r] = fmaf(xv.z, w2, acc[r]);
                acc[r] = fmaf(xv.w, w3, acc[r]);
            }
        }
    }
    float avs = atts[lane], avd = attd[lane];
#pragma unroll
    for (int r = 0; r < 8; r++) {
        if (r < rmax) {
            int row = r0 + r;
            Gb[(size_t)row * 64 + lane] = f2bf(acc[r]);
            float vs = acc[r] * avs, vd = acc[r] * avd;
#pragma unroll
            for (int off = 1; off < 64; off <<= 1) {
                vs += __shfl_xor(vs, off, 64);
                vd += __shfl_xor(vd, off, 64);
            }
            if (lane == 0) { asrc[row] = vs; adst[row] = vd; }
        }
    }
}

// ---------------- Fused per-dst gather (softmax + aggregate) ----------------
__global__ __launch_bounds__(256) void k_gather1(const int* __restrict__ rowptr,
                                                 const int* __restrict__ col,
                                                 const unsigned short* __restrict__ Hb,
                                                 const float* __restrict__ asrc,
                                                 const float* __restrict__ adst,
                                                 const float* __restrict__ bias,
                                                 int N, float* __restrict__ out) {
    int lane = threadIdx.x & 63;
    int d = (blockIdx.x << 2) + (threadIdx.x >> 6);
    if (d >= N) return;
    int h = lane >> 3;
    float adv = adst[d * 8 + h];
    int jb = rowptr[d], je = rowptr[d + 1];
    float acc = 0.f, denom = 0.f;
    for (int j = jb; j < je; ++j) {
        int s = col[j];
        float e = asrc[s * 8 + h] + adv;
        e = (e > 0.f) ? e : LRELU * e;
        float w = __expf(e);
        denom += w;
        acc = fmaf(w, bf2f(Hb[(size_t)s * 64 + lane]), acc);
    }
    float v = acc / (denom + 1e-16f) + bias[lane];
    out[(size_t)d * 64 + lane] = (v > 0.f) ? v : expm1f(v);   // ELU(alpha=1)
}

__global__ __launch_bounds__(256) void k_gather2(const int* __restrict__ rowptr,
                                                 const int* __restrict__ col,
                                                 const unsigned short* __restrict__ Gb,
                                                 const float* __restrict__ asrc,
                                                 const float* __restrict__ adst,
                                                 const float* __restrict__ bias,
                                                 int N, float* __restrict__ out) {
    int lane = threadIdx.x & 63;
    int d = (blockIdx.x << 2) + (threadIdx.x >> 6);
    if (d >= N) return;
    float adv = adst[d];
    int jb = rowptr[d], je = rowptr[d + 1];
    float acc = 0.f, denom = 0.f;
    for (int j = jb; j < je; ++j) {
        int s = col[j];
        float e = asrc[s] + adv;
        e = (e > 0.f) ? e : LRELU * e;
        float w = __expf(e);
        denom += w;
        acc = fmaf(w, bf2f(Gb[(size_t)s * 64 + lane]), acc);
    }
    float v = acc / (denom + 1e-16f) + bias[lane];
    // log_softmax across the wave (64 lanes = 64 classes)
    float m = v;
#pragma unroll
    for (int off = 1; off < 64; off <<= 1) m = fmaxf(m, __shfl_xor(m, off, 64));
    float ex = __expf(v - m);
    float ssum = ex;
#pragma unroll
    for (int off = 1; off < 64; off <<= 1) ssum += __shfl_xor(ssum, off, 64);
    out[(size_t)d * 64 + lane] = v - m - __logf(ssum);
}

// ---------------- launch ----------------

extern "C" void kernel_launch(void* const* d_in, const int* in_sizes, int n_in,
                              void* d_out, int out_size, void* d_ws, size_t ws_size,
                              hipStream_t stream) {
    const float* x   = (const float*)d_in[0];
    const int*   ei  = (const int*)d_in[1];
    const float* W1  = (const float*)d_in[2];
    const float* as1 = (const float*)d_in[3];
    const float* ad1 = (const float*)d_in[4];
    const float* b1  = (const float*)d_in[5];
    const float* W2  = (const float*)d_in[6];
    const float* as2 = (const float*)d_in[7];
    const float* ad2 = (const float*)d_in[8];
    const float* b2  = (const float*)d_in[9];
    float* out = (float*)d_out;

    const int N = in_sizes[0] / 256;
    const int E = in_sizes[1] / 2;
    const int* src = ei;
    const int* dst = ei + E;

    char* ws = (char*)d_ws;
    size_t off = 0;
    auto alloc = [&](size_t bytes) -> void* {
        void* p = ws + off;
        off = (off + bytes + 255) & ~(size_t)255;
        return p;
    };
    const int nb = (N + 1023) / 1024;
    int*   deg    = (int*)alloc((size_t)N * 4);
    int*   rowptr = (int*)alloc((size_t)(N + 1) * 4);
    int*   cursor = (int*)alloc((size_t)N * 4);
    int*   bsum   = (int*)alloc((size_t)nb * 4);
    int*   boff   = (int*)alloc((size_t)nb * 4);
    int*   col    = (int*)alloc((size_t)E * 4);
    unsigned short* h1b = (unsigned short*)alloc((size_t)N * 64 * 2);
    float* a_s1   = (float*)alloc((size_t)N * 8 * 4);
    float* a_d1   = (float*)alloc((size_t)N * 8 * 4);
    float* h2     = (float*)alloc((size_t)N * 64 * 4);
    unsigned short* gb = (unsigned short*)alloc((size_t)N * 64 * 2);
    float* a_s2   = (float*)alloc((size_t)N * 4);
    float* a_d2   = (float*)alloc((size_t)N * 4);
    (void)ws_size; (void)n_in; (void)out_size;

    hipMemsetAsync(deg, 0, (size_t)N * 4, stream);
    k_hist<<<2048, 256, 0, stream>>>(dst, E, deg);
    k_partsum<<<nb, 256, 0, stream>>>(deg, N, bsum);
    k_scansum<<<1, 64, 0, stream>>>(bsum, nb, boff, rowptr, N);
    k_scanwrite<<<nb, 256, 0, stream>>>(deg, N, boff, rowptr, cursor);
    k_scatter<<<2048, 256, 0, stream>>>(src, dst, E, cursor, col);

    int waves = (N + 7) / 8;
    int gemm_blocks = (waves + 3) / 4;
    k_gemm1<<<gemm_blocks, 256, 0, stream>>>(x, W1, as1, ad1, N, h1b, a_s1, a_d1);

    int gather_blocks = (N + 3) / 4;
    k_gather1<<<gather_blocks, 256, 0, stream>>>(rowptr, col, h1b, a_s1, a_d1, b1, N, h2);

    k_gemm2<<<gemm_blocks, 256, 0, stream>>>(h2, W2, as2, ad2, N, gb, a_s2, a_d2);

    k_gather2<<<gather_blocks, 256, 0, stream>>>(rowptr, col, gb, a_s2, a_d2, b2, N, out);
}

// Round 3
// 586.427 us; speedup vs baseline: 1.4795x; 1.2862x over previous
//
#include <hip/hip_runtime.h>
#include <math.h>

#define LRELU 0.2f

static __device__ __forceinline__ float bf2f(unsigned int u16) {
    union { unsigned int i; float f; } c; c.i = u16 << 16; return c.f;
}
static __device__ __forceinline__ unsigned short f2bf(float f) {
    union { float f; unsigned int i; } c; c.f = f;
    unsigned int x = c.i;
    return (unsigned short)((x + 0x7fffu + ((x >> 16) & 1u)) >> 16);  // RNE
}

// ---------------- CSR build ----------------

__global__ void k_hist(const int* __restrict__ dst, int E, int* __restrict__ deg) {
    int i = blockIdx.x * blockDim.x + threadIdx.x;
    int stride = gridDim.x * blockDim.x;
    for (; i < E; i += stride) atomicAdd(&deg[dst[i]], 1);
}

__global__ __launch_bounds__(256) void k_partsum(const int* __restrict__ deg, int N,
                                                 int* __restrict__ bsum) {
    int t = threadIdx.x, lane = t & 63, wv = t >> 6;
    int base = blockIdx.x * 1024 + t * 4;
    int s = 0;
    if (base + 3 < N) {
        int4 v = *reinterpret_cast<const int4*>(deg + base);
        s = v.x + v.y + v.z + v.w;
    } else {
        for (int i = 0; i < 4; ++i) if (base + i < N) s += deg[base + i];
    }
#pragma unroll
    for (int off = 1; off < 64; off <<= 1) s += __shfl_xor(s, off, 64);
    __shared__ int ws[4];
    if (lane == 0) ws[wv] = s;
    __syncthreads();
    if (t == 0) bsum[blockIdx.x] = ws[0] + ws[1] + ws[2] + ws[3];
}

__global__ __launch_bounds__(64) void k_scansum(const int* __restrict__ bsum, int nb,
                                                int* __restrict__ boff,
                                                int* __restrict__ rowptr, int N) {
    int lane = threadIdx.x;
    int run = 0;
    for (int base = 0; base < nb; base += 64) {
        int v = (base + lane < nb) ? bsum[base + lane] : 0;
        int inc = v;
#pragma unroll
        for (int off = 1; off < 64; off <<= 1) {
            int t = __shfl_up(inc, off, 64);
            if (lane >= off) inc += t;
        }
        if (base + lane < nb) boff[base + lane] = run + inc - v;
        run += __shfl(inc, 63, 64);
    }
    if (lane == 0) rowptr[N] = run;
}

__global__ __launch_bounds__(256) void k_scanwrite(const int* __restrict__ deg, int N,
                                                   const int* __restrict__ boff,
                                                   int* __restrict__ rowptr,
                                                   int* __restrict__ cursor) {
    int t = threadIdx.x, lane = t & 63, wv = t >> 6;
    int base = blockIdx.x * 1024 + t * 4;
    int v[4] = {0, 0, 0, 0};
    if (base + 3 < N) {
        int4 q = *reinterpret_cast<const int4*>(deg + base);
        v[0] = q.x; v[1] = q.y; v[2] = q.z; v[3] = q.w;
    } else {
        for (int i = 0; i < 4; ++i) if (base + i < N) v[i] = deg[base + i];
    }
    int s = v[0] + v[1] + v[2] + v[3];
    int inc = s;
#pragma unroll
    for (int off = 1; off < 64; off <<= 1) {
        int q = __shfl_up(inc, off, 64);
        if (lane >= off) inc += q;
    }
    __shared__ int wtot[4];
    if (lane == 63) wtot[wv] = inc;
    __syncthreads();
    int woff = 0;
    for (int w = 0; w < wv; ++w) woff += wtot[w];
    int excl = woff + inc - s + boff[blockIdx.x];
    for (int i = 0; i < 4; ++i) {
        if (base + i < N) {
            rowptr[base + i] = excl;
            cursor[base + i] = excl;
            excl += v[i];
        }
    }
}

__global__ void k_scatter(const int* __restrict__ src, const int* __restrict__ dst,
                          int E, int* __restrict__ cursor, int* __restrict__ col) {
    int i = blockIdx.x * blockDim.x + threadIdx.x;
    int stride = gridDim.x * blockDim.x;
    for (; i < E; i += stride) {
        int d = dst[i];
        int p = atomicAdd(&cursor[d], 1);
        col[p] = src[i];
    }
}

// ---------------- GEMM + attention projections ----------------

__global__ __launch_bounds__(256) void k_gemm1(const float* __restrict__ X,
                                               const float* __restrict__ W,
                                               const float* __restrict__ atts,
                                               const float* __restrict__ attd,
                                               int N, unsigned short* __restrict__ Hb,
                                               float* __restrict__ asrc,
                                               float* __restrict__ adst) {
    int lane = threadIdx.x & 63;
    int wave = (blockIdx.x << 2) + (threadIdx.x >> 6);
    int r0 = wave * 8;
    if (r0 >= N) return;
    int rmax = N - r0; if (rmax > 8) rmax = 8;

    float acc[8] = {0.f, 0.f, 0.f, 0.f, 0.f, 0.f, 0.f, 0.f};
    for (int k = 0; k < 256; k += 4) {
        float w0 = W[(k + 0) * 64 + lane];
        float w1 = W[(k + 1) * 64 + lane];
        float w2 = W[(k + 2) * 64 + lane];
        float w3 = W[(k + 3) * 64 + lane];
#pragma unroll
        for (int r = 0; r < 8; r++) {
            if (r < rmax) {
                float4 xv = *reinterpret_cast<const float4*>(X + (size_t)(r0 + r) * 256 + k);
                acc[r] = fmaf(xv.x, w0, acc[r]);
                acc[r] = fmaf(xv.y, w1, acc[r]);
                acc[r] = fmaf(xv.z, w2, acc[r]);
                acc[r] = fmaf(xv.w, w3, acc[r]);
            }
        }
    }
    float avs = atts[lane], avd = attd[lane];
#pragma unroll
    for (int r = 0; r < 8; r++) {
        if (r < rmax) {
            int row = r0 + r;
            Hb[(size_t)row * 64 + lane] = f2bf(acc[r]);
            float vs = acc[r] * avs, vd = acc[r] * avd;
            vs += __shfl_xor(vs, 1, 64); vs += __shfl_xor(vs, 2, 64); vs += __shfl_xor(vs, 4, 64);
            vd += __shfl_xor(vd, 1, 64); vd += __shfl_xor(vd, 2, 64); vd += __shfl_xor(vd, 4, 64);
            if ((lane & 7) == 0) {
                asrc[row * 8 + (lane >> 3)] = vs;
                adst[row * 8 + (lane >> 3)] = vd;
            }
        }
    }
}

__global__ __launch_bounds__(256) void k_gemm2(const float* __restrict__ X,
                                               const float* __restrict__ W,
                                               const float* __restrict__ atts,
                                               const float* __restrict__ attd,
                                               int N, unsigned short* __restrict__ Gb,
                                               float* __restrict__ asrc,
                                               float* __restrict__ adst) {
    int lane = threadIdx.x & 63;
    int wave = (blockIdx.x << 2) + (threadIdx.x >> 6);
    int r0 = wave * 8;
    if (r0 >= N) return;
    int rmax = N - r0; if (rmax > 8) rmax = 8;

    float acc[8] = {0.f, 0.f, 0.f, 0.f, 0.f, 0.f, 0.f, 0.f};
    for (int k = 0; k < 64; k += 4) {
        float w0 = W[(k + 0) * 64 + lane];
        float w1 = W[(k + 1) * 64 + lane];
        float w2 = W[(k + 2) * 64 + lane];
        float w3 = W[(k + 3) * 64 + lane];
#pragma unroll
        for (int r = 0; r < 8; r++) {
            if (r < rmax) {
                float4 xv = *reinterpret_cast<const float4*>(X + (size_t)(r0 + r) * 64 + k);
                acc[r] = fmaf(xv.x, w0, acc[r]);
                acc[r] = fmaf(xv.y, w1, acc[r]);
                acc[r] = fmaf(xv.z, w2, acc[r]);
                acc[r] = fmaf(xv.w, w3, acc[r]);
            }
        }
    }
    float avs = atts[lane], avd = attd[lane];
#pragma unroll
    for (int r = 0; r < 8; r++) {
        if (r < rmax) {
            int row = r0 + r;
            Gb[(size_t)row * 64 + lane] = f2bf(acc[r]);
            float vs = acc[r] * avs, vd = acc[r] * avd;
#pragma unroll
            for (int off = 1; off < 64; off <<= 1) {
                vs += __shfl_xor(vs, off, 64);
                vd += __shfl_xor(vd, off, 64);
            }
            if (lane == 0) { asrc[row] = vs; adst[row] = vd; }
        }
    }
}

// ---------------- Fused per-dst gather, 4 edges in flight ----------------
// Wave per dst. g=lane>>4 picks edge within a 4-edge batch; sub=lane&15 picks
// channel quad [4*sub, 4*sub+3]. Each lane loads uint2 (4 bf16 ch) per batch.

__global__ __launch_bounds__(256) void k_gather1(const int* __restrict__ rowptr,
                                                 const int* __restrict__ col,
                                                 const uint2* __restrict__ Hb4,
                                                 const float* __restrict__ asrc,
                                                 const float* __restrict__ adst,
                                                 const float4* __restrict__ bias4,
                                                 int N, float4* __restrict__ out4) {
    int lane = threadIdx.x & 63;
    int d = (blockIdx.x << 2) + (threadIdx.x >> 6);
    if (d >= N) return;
    int g = lane >> 4;        // edge slot within batch of 4
    int sub = lane & 15;      // channel quad
    int head = sub >> 1;      // channels 4*sub.. belong to this head
    float adv = adst[d * 8 + head];
    int jb = rowptr[d], je = rowptr[d + 1];

    float4 acc = {0.f, 0.f, 0.f, 0.f};
    float denom = 0.f;
    for (int base = jb; base < je; base += 64) {
        int cnt = je - base; if (cnt > 64) cnt = 64;
        int myCol = (lane < cnt) ? col[base + lane] : 0;
#pragma unroll 2
        for (int u = 0; u < cnt; u += 4) {
            int eg = u + g;                       // <= 63 always
            int s = __shfl(myCol, eg, 64);
            float e = asrc[s * 8 + head] + adv;
            e = (e > 0.f) ? e : LRELU * e;
            float w = (eg < cnt) ? __expf(e) : 0.f;
            uint2 hv = Hb4[(size_t)s * 16 + sub];
            denom += w;
            acc.x = fmaf(w, bf2f(hv.x & 0xffffu), acc.x);
            acc.y = fmaf(w, bf2f(hv.x >> 16), acc.y);
            acc.z = fmaf(w, bf2f(hv.y & 0xffffu), acc.z);
            acc.w = fmaf(w, bf2f(hv.y >> 16), acc.w);
        }
    }
    // combine the 4 edge groups
#pragma unroll
    for (int off = 16; off < 64; off <<= 1) {
        acc.x += __shfl_xor(acc.x, off, 64);
        acc.y += __shfl_xor(acc.y, off, 64);
        acc.z += __shfl_xor(acc.z, off, 64);
        acc.w += __shfl_xor(acc.w, off, 64);
        denom += __shfl_xor(denom, off, 64);
    }
    if (lane < 16) {
        float invd = 1.f / (denom + 1e-16f);
        float4 b = bias4[sub];
        float4 v;
        v.x = fmaf(acc.x, invd, b.x);
        v.y = fmaf(acc.y, invd, b.y);
        v.z = fmaf(acc.z, invd, b.z);
        v.w = fmaf(acc.w, invd, b.w);
        v.x = (v.x > 0.f) ? v.x : expm1f(v.x);
        v.y = (v.y > 0.f) ? v.y : expm1f(v.y);
        v.z = (v.z > 0.f) ? v.z : expm1f(v.z);
        v.w = (v.w > 0.f) ? v.w : expm1f(v.w);
        out4[(size_t)d * 16 + sub] = v;
    }
}

__global__ __launch_bounds__(256) void k_gather2(const int* __restrict__ rowptr,
                                                 const int* __restrict__ col,
                                                 const uint2* __restrict__ Gb4,
                                                 const float* __restrict__ asrc,
                                                 const float* __restrict__ adst,
                                                 const float4* __restrict__ bias4,
                                                 int N, float4* __restrict__ out4) {
    int lane = threadIdx.x & 63;
    int d = (blockIdx.x << 2) + (threadIdx.x >> 6);
    if (d >= N) return;
    int g = lane >> 4;
    int sub = lane & 15;
    float adv = adst[d];
    int jb = rowptr[d], je = rowptr[d + 1];

    float4 acc = {0.f, 0.f, 0.f, 0.f};
    float denom = 0.f;
    for (int base = jb; base < je; base += 64) {
        int cnt = je - base; if (cnt > 64) cnt = 64;
        int myCol = (lane < cnt) ? col[base + lane] : 0;
#pragma unroll 2
        for (int u = 0; u < cnt; u += 4) {
            int eg = u + g;
            int s = __shfl(myCol, eg, 64);
            float e = asrc[s] + adv;
            e = (e > 0.f) ? e : LRELU * e;
            float w = (eg < cnt) ? __expf(e) : 0.f;
            uint2 hv = Gb4[(size_t)s * 16 + sub];
            denom += w;
            acc.x = fmaf(w, bf2f(hv.x & 0xffffu), acc.x);
            acc.y = fmaf(w, bf2f(hv.x >> 16), acc.y);
            acc.z = fmaf(w, bf2f(hv.y & 0xffffu), acc.z);
            acc.w = fmaf(w, bf2f(hv.y >> 16), acc.w);
        }
    }
#pragma unroll
    for (int off = 16; off < 64; off <<= 1) {
        acc.x += __shfl_xor(acc.x, off, 64);
        acc.y += __shfl_xor(acc.y, off, 64);
        acc.z += __shfl_xor(acc.z, off, 64);
        acc.w += __shfl_xor(acc.w, off, 64);
        denom += __shfl_xor(denom, off, 64);
    }
    // all lanes now hold full sums for their channel quad
    float invd = 1.f / (denom + 1e-16f);
    float4 b = bias4[sub];
    float4 v;
    v.x = fmaf(acc.x, invd, b.x);
    v.y = fmaf(acc.y, invd, b.y);
    v.z = fmaf(acc.z, invd, b.z);
    v.w = fmaf(acc.w, invd, b.w);
    // log_softmax over the 64 channels (16 quads)
    float m = fmaxf(fmaxf(v.x, v.y), fmaxf(v.z, v.w));
#pragma unroll
    for (int off = 1; off < 16; off <<= 1) m = fmaxf(m, __shfl_xor(m, off, 64));
    float se = __expf(v.x - m) + __expf(v.y - m) + __expf(v.z - m) + __expf(v.w - m);
#pragma unroll
    for (int off = 1; off < 16; off <<= 1) se += __shfl_xor(se, off, 64);
    float ls = m + __logf(se);
    if (lane < 16) {
        v.x -= ls; v.y -= ls; v.z -= ls; v.w -= ls;
        out4[(size_t)d * 16 + sub] = v;
    }
}

// ---------------- launch ----------------

extern "C" void kernel_launch(void* const* d_in, const int* in_sizes, int n_in,
                              void* d_out, int out_size, void* d_ws, size_t ws_size,
                              hipStream_t stream) {
    const float* x   = (const float*)d_in[0];
    const int*   ei  = (const int*)d_in[1];
    const float* W1  = (const float*)d_in[2];
    const float* as1 = (const float*)d_in[3];
    const float* ad1 = (const float*)d_in[4];
    const float* b1  = (const float*)d_in[5];
    const float* W2  = (const float*)d_in[6];
    const float* as2 = (const float*)d_in[7];
    const float* ad2 = (const float*)d_in[8];
    const float* b2  = (const float*)d_in[9];
    float* out = (float*)d_out;

    const int N = in_sizes[0] / 256;
    const int E = in_sizes[1] / 2;
    const int* src = ei;
    const int* dst = ei + E;

    char* ws = (char*)d_ws;
    size_t off = 0;
    auto alloc = [&](size_t bytes) -> void* {
        void* p = ws + off;
        off = (off + bytes + 255) & ~(size_t)255;
        return p;
    };
    const int nb = (N + 1023) / 1024;
    int*   deg    = (int*)alloc((size_t)N * 4);
    int*   rowptr = (int*)alloc((size_t)(N + 1) * 4);
    int*   cursor = (int*)alloc((size_t)N * 4);
    int*   bsum   = (int*)alloc((size_t)nb * 4);
    int*   boff   = (int*)alloc((size_t)nb * 4);
    int*   col    = (int*)alloc((size_t)E * 4);
    unsigned short* h1b = (unsigned short*)alloc((size_t)N * 64 * 2);
    float* a_s1   = (float*)alloc((size_t)N * 8 * 4);
    float* a_d1   = (float*)alloc((size_t)N * 8 * 4);
    float* h2     = (float*)alloc((size_t)N * 64 * 4);
    unsigned short* gb = (unsigned short*)alloc((size_t)N * 64 * 2);
    float* a_s2   = (float*)alloc((size_t)N * 4);
    float* a_d2   = (float*)alloc((size_t)N * 4);
    (void)ws_size; (void)n_in; (void)out_size;

    hipMemsetAsync(deg, 0, (size_t)N * 4, stream);
    k_hist<<<2048, 256, 0, stream>>>(dst, E, deg);
    k_partsum<<<nb, 256, 0, stream>>>(deg, N, bsum);
    k_scansum<<<1, 64, 0, stream>>>(bsum, nb, boff, rowptr, N);
    k_scanwrite<<<nb, 256, 0, stream>>>(deg, N, boff, rowptr, cursor);
    k_scatter<<<2048, 256, 0, stream>>>(src, dst, E, cursor, col);

    int waves = (N + 7) / 8;
    int gemm_blocks = (waves + 3) / 4;
    k_gemm1<<<gemm_blocks, 256, 0, stream>>>(x, W1, as1, ad1, N, h1b, a_s1, a_d1);

    int gather_blocks = (N + 3) / 4;
    k_gather1<<<gather_blocks, 256, 0, stream>>>(rowptr, col, (const uint2*)h1b,
                                                 a_s1, a_d1, (const float4*)b1, N,
                                                 (float4*)h2);

    k_gemm2<<<gemm_blocks, 256, 0, stream>>>(h2, W2, as2, ad2, N, gb, a_s2, a_d2);

    k_gather2<<<gather_blocks, 256, 0, stream>>>(rowptr, col, (const uint2*)gb,
                                                 a_s2, a_d2, (const float4*)b2, N,
                                                 (float4*)out);
}

// Round 4
// 445.443 us; speedup vs baseline: 1.9478x; 1.3165x over previous
//
#include <hip/hip_runtime.h>
#include <math.h>

#define LRELU 0.2f

typedef __attribute__((ext_vector_type(8))) short bf16x8;
typedef __attribute__((ext_vector_type(4))) float f32x4;

static __device__ __forceinline__ float bf2f(unsigned int u16) {
    union { unsigned int i; float f; } c; c.i = u16 << 16; return c.f;
}
static __device__ __forceinline__ unsigned short f2bf(float f) {
    union { float f; unsigned int i; } c; c.f = f;
    unsigned int x = c.i;
    return (unsigned short)((x + 0x7fffu + ((x >> 16) & 1u)) >> 16);  // RNE
}

// ---------------- CSR build ----------------

__global__ void k_hist(const int* __restrict__ dst, int E, int* __restrict__ deg) {
    int i = blockIdx.x * blockDim.x + threadIdx.x;
    int stride = gridDim.x * blockDim.x;
    for (; i < E; i += stride) atomicAdd(&deg[dst[i]], 1);
}

__global__ __launch_bounds__(256) void k_partsum(const int* __restrict__ deg, int N,
                                                 int* __restrict__ bsum) {
    int t = threadIdx.x, lane = t & 63, wv = t >> 6;
    int base = blockIdx.x * 1024 + t * 4;
    int s = 0;
    if (base + 3 < N) {
        int4 v = *reinterpret_cast<const int4*>(deg + base);
        s = v.x + v.y + v.z + v.w;
    } else {
        for (int i = 0; i < 4; ++i) if (base + i < N) s += deg[base + i];
    }
#pragma unroll
    for (int off = 1; off < 64; off <<= 1) s += __shfl_xor(s, off, 64);
    __shared__ int ws[4];
    if (lane == 0) ws[wv] = s;
    __syncthreads();
    if (t == 0) bsum[blockIdx.x] = ws[0] + ws[1] + ws[2] + ws[3];
}

__global__ __launch_bounds__(64) void k_scansum(const int* __restrict__ bsum, int nb,
                                                int* __restrict__ boff,
                                                int* __restrict__ rowptr, int N) {
    int lane = threadIdx.x;
    int run = 0;
    for (int base = 0; base < nb; base += 64) {
        int v = (base + lane < nb) ? bsum[base + lane] : 0;
        int inc = v;
#pragma unroll
        for (int off = 1; off < 64; off <<= 1) {
            int t = __shfl_up(inc, off, 64);
            if (lane >= off) inc += t;
        }
        if (base + lane < nb) boff[base + lane] = run + inc - v;
        run += __shfl(inc, 63, 64);
    }
    if (lane == 0) rowptr[N] = run;
}

__global__ __launch_bounds__(256) void k_scanwrite(const int* __restrict__ deg, int N,
                                                   const int* __restrict__ boff,
                                                   int* __restrict__ rowptr,
                                                   int* __restrict__ cursor) {
    int t = threadIdx.x, lane = t & 63, wv = t >> 6;
    int base = blockIdx.x * 1024 + t * 4;
    int v[4] = {0, 0, 0, 0};
    if (base + 3 < N) {
        int4 q = *reinterpret_cast<const int4*>(deg + base);
        v[0] = q.x; v[1] = q.y; v[2] = q.z; v[3] = q.w;
    } else {
        for (int i = 0; i < 4; ++i) if (base + i < N) v[i] = deg[base + i];
    }
    int s = v[0] + v[1] + v[2] + v[3];
    int inc = s;
#pragma unroll
    for (int off = 1; off < 64; off <<= 1) {
        int q = __shfl_up(inc, off, 64);
        if (lane >= off) inc += q;
    }
    __shared__ int wtot[4];
    if (lane == 63) wtot[wv] = inc;
    __syncthreads();
    int woff = 0;
    for (int w = 0; w < wv; ++w) woff += wtot[w];
    int excl = woff + inc - s + boff[blockIdx.x];
    for (int i = 0; i < 4; ++i) {
        if (base + i < N) {
            rowptr[base + i] = excl;
            cursor[base + i] = excl;
            excl += v[i];
        }
    }
}

__global__ void k_scatter(const int* __restrict__ src, const int* __restrict__ dst,
                          int E, int* __restrict__ cursor, int* __restrict__ col) {
    int i = blockIdx.x * blockDim.x + threadIdx.x;
    int stride = gridDim.x * blockDim.x;
    for (; i < E; i += stride) {
        int d = dst[i];
        int p = atomicAdd(&cursor[d], 1);
        col[p] = src[i];
    }
}

// ---------------- weight convert/transpose to bf16 ----------------
// Wt1[n][k] = W1[k][n]  (64 x 256), Wt2[n][k] = W2[k][n]  (64 x 64)
__global__ __launch_bounds__(256) void k_cvtW(const float* __restrict__ W1,
                                              const float* __restrict__ W2,
                                              unsigned short* __restrict__ Wt1,
                                              unsigned short* __restrict__ Wt2) {
    int idx = blockIdx.x * 256 + threadIdx.x;
    if (idx < 16384) {
        int n = idx >> 8, k = idx & 255;
        Wt1[idx] = f2bf(W1[k * 64 + n]);
    } else if (idx < 16384 + 4096) {
        int j = idx - 16384;
        int n = j >> 6, k = j & 63;
        Wt2[j] = f2bf(W2[k * 64 + n]);
    }
}

// ---------------- MFMA GEMM1: X[N,256] fp32 -> H[N,64] bf16 + per-head att ----
// Block = 64 rows (4 waves x 16 rows). Wave-local LDS staging of X as bf16,
// XOR-swizzled 16B granules. B fragments from global Wt1 (bf16, n-major).
__global__ __launch_bounds__(256) void k_gemm1m(const float* __restrict__ X,
                                                const unsigned short* __restrict__ Wt,
                                                const float* __restrict__ atts,
                                                const float* __restrict__ attd,
                                                int N, unsigned short* __restrict__ Hb,
                                                float* __restrict__ asrc,
                                                float* __restrict__ adst) {
    __shared__ short Xl[64 * 256];
    int t = threadIdx.x, l = t & 63, w = t >> 6;
    int rblk = blockIdx.x * 64;

    // stage 16 rows (this wave's) fp32 -> bf16 LDS
    int half = l >> 5;            // 0/1: which row of the pair
    int c8 = (l & 31) * 8;        // starting col, 8 per lane
#pragma unroll
    for (int i = 0; i < 8; ++i) {
        int rl = w * 16 + i * 2 + half;
        int row = rblk + rl;
        float4 x0 = {0.f, 0.f, 0.f, 0.f}, x1 = {0.f, 0.f, 0.f, 0.f};
        if (row < N) {
            x0 = *reinterpret_cast<const float4*>(X + (size_t)row * 256 + c8);
            x1 = *reinterpret_cast<const float4*>(X + (size_t)row * 256 + c8 + 4);
        }
        bf16x8 p;
        p[0] = (short)f2bf(x0.x); p[1] = (short)f2bf(x0.y);
        p[2] = (short)f2bf(x0.z); p[3] = (short)f2bf(x0.w);
        p[4] = (short)f2bf(x1.x); p[5] = (short)f2bf(x1.y);
        p[6] = (short)f2bf(x1.z); p[7] = (short)f2bf(x1.w);
        int g = (l & 31) ^ (rl & 7);
        *reinterpret_cast<bf16x8*>(&Xl[rl * 256 + g * 8]) = p;
    }
    // wave-local LDS use: no __syncthreads needed (compiler waits lgkmcnt)

    int m = l & 15, quad = l >> 4;
    int rl = w * 16 + m;
    f32x4 acc0 = {0.f, 0.f, 0.f, 0.f}, acc1 = acc0, acc2 = acc0, acc3 = acc0;
#pragma unroll
    for (int tt = 0; tt < 8; ++tt) {
        int g = (tt * 4 + quad) ^ (m & 7);
        bf16x8 a = *reinterpret_cast<const bf16x8*>(&Xl[rl * 256 + g * 8]);
        int kk = tt * 32 + quad * 8;
        bf16x8 b0 = *reinterpret_cast<const bf16x8*>(&Wt[(0 * 16 + m) * 256 + kk]);
        bf16x8 b1 = *reinterpret_cast<const bf16x8*>(&Wt[(1 * 16 + m) * 256 + kk]);
        bf16x8 b2 = *reinterpret_cast<const bf16x8*>(&Wt[(2 * 16 + m) * 256 + kk]);
        bf16x8 b3 = *reinterpret_cast<const bf16x8*>(&Wt[(3 * 16 + m) * 256 + kk]);
        acc0 = __builtin_amdgcn_mfma_f32_16x16x32_bf16(a, b0, acc0, 0, 0, 0);
        acc1 = __builtin_amdgcn_mfma_f32_16x16x32_bf16(a, b1, acc1, 0, 0, 0);
        acc2 = __builtin_amdgcn_mfma_f32_16x16x32_bf16(a, b2, acc2, 0, 0, 0);
        acc3 = __builtin_amdgcn_mfma_f32_16x16x32_bf16(a, b3, acc3, 0, 0, 0);
    }

    // epilogue: D layout col=lane&15 (+16*nt), row=quad*4+reg
    int r0 = rblk + w * 16;
    f32x4 accs[4] = {acc0, acc1, acc2, acc3};
#pragma unroll
    for (int nt = 0; nt < 4; ++nt) {
        int cn = nt * 16 + m;
        float av_s = atts[cn], av_d = attd[cn];
#pragma unroll
        for (int r = 0; r < 4; ++r) {
            int row = r0 + quad * 4 + r;
            float hv = accs[nt][r];
            if (row < N) Hb[(size_t)row * 64 + cn] = f2bf(hv);
            float vs = hv * av_s, vd = hv * av_d;
            vs += __shfl_xor(vs, 1, 64); vs += __shfl_xor(vs, 2, 64); vs += __shfl_xor(vs, 4, 64);
            vd += __shfl_xor(vd, 1, 64); vd += __shfl_xor(vd, 2, 64); vd += __shfl_xor(vd, 4, 64);
            if ((m & 7) == 0 && row < N) {
                int head = cn >> 3;
                asrc[row * 8 + head] = vs;
                adst[row * 8 + head] = vd;
            }
        }
    }
}

// ---------------- MFMA GEMM2: Xb[N,64] bf16 -> G[N,64] bf16 + att (1 head) ----
__global__ __launch_bounds__(256) void k_gemm2m(const unsigned short* __restrict__ Xb,
                                                const unsigned short* __restrict__ Wt,
                                                const float* __restrict__ atts,
                                                const float* __restrict__ attd,
                                                int N, unsigned short* __restrict__ Gb,
                                                float* __restrict__ asrc,
                                                float* __restrict__ adst) {
    int t = threadIdx.x, l = t & 63, w = t >> 6;
    int rblk = blockIdx.x * 64;
    int m = l & 15, quad = l >> 4;
    int row = rblk + w * 16 + m;
    int rowc = (row < N) ? row : 0;

    f32x4 acc0 = {0.f, 0.f, 0.f, 0.f}, acc1 = acc0, acc2 = acc0, acc3 = acc0;
#pragma unroll
    for (int tt = 0; tt < 2; ++tt) {
        int kk = tt * 32 + quad * 8;
        bf16x8 a = *reinterpret_cast<const bf16x8*>(&Xb[(size_t)rowc * 64 + kk]);
        bf16x8 b0 = *reinterpret_cast<const bf16x8*>(&Wt[(0 * 16 + m) * 64 + kk]);
        bf16x8 b1 = *reinterpret_cast<const bf16x8*>(&Wt[(1 * 16 + m) * 64 + kk]);
        bf16x8 b2 = *reinterpret_cast<const bf16x8*>(&Wt[(2 * 16 + m) * 64 + kk]);
        bf16x8 b3 = *reinterpret_cast<const bf16x8*>(&Wt[(3 * 16 + m) * 64 + kk]);
        acc0 = __builtin_amdgcn_mfma_f32_16x16x32_bf16(a, b0, acc0, 0, 0, 0);
        acc1 = __builtin_amdgcn_mfma_f32_16x16x32_bf16(a, b1, acc1, 0, 0, 0);
        acc2 = __builtin_amdgcn_mfma_f32_16x16x32_bf16(a, b2, acc2, 0, 0, 0);
        acc3 = __builtin_amdgcn_mfma_f32_16x16x32_bf16(a, b3, acc3, 0, 0, 0);
    }

    int r0 = rblk + w * 16;
    f32x4 accs[4] = {acc0, acc1, acc2, acc3};
#pragma unroll
    for (int r = 0; r < 4; ++r) {
        int orow = r0 + quad * 4 + r;
        float vs = 0.f, vd = 0.f;
#pragma unroll
        for (int nt = 0; nt < 4; ++nt) {
            int cn = nt * 16 + m;
            float hv = accs[nt][r];
            if (orow < N) Gb[(size_t)orow * 64 + cn] = f2bf(hv);
            vs = fmaf(hv, atts[cn], vs);
            vd = fmaf(hv, attd[cn], vd);
        }
#pragma unroll
        for (int off = 1; off < 16; off <<= 1) {
            vs += __shfl_xor(vs, off, 64);
            vd += __shfl_xor(vd, off, 64);
        }
        if (m == 0 && orow < N) { asrc[orow] = vs; adst[orow] = vd; }
    }
}

// ---------------- Fused per-dst gather, 4 edges in flight ----------------

__global__ __launch_bounds__(256) void k_gather1(const int* __restrict__ rowptr,
                                                 const int* __restrict__ col,
                                                 const uint2* __restrict__ Hb4,
                                                 const float* __restrict__ asrc,
                                                 const float* __restrict__ adst,
                                                 const float4* __restrict__ bias4,
                                                 int N, unsigned short* __restrict__ outb) {
    int lane = threadIdx.x & 63;
    int d = (blockIdx.x << 2) + (threadIdx.x >> 6);
    if (d >= N) return;
    int g = lane >> 4;        // edge slot within batch of 4
    int sub = lane & 15;      // channel quad
    int head = sub >> 1;
    float adv = adst[d * 8 + head];
    int jb = rowptr[d], je = rowptr[d + 1];

    float4 acc = {0.f, 0.f, 0.f, 0.f};
    float denom = 0.f;
    for (int base = jb; base < je; base += 64) {
        int cnt = je - base; if (cnt > 64) cnt = 64;
        int myCol = (lane < cnt) ? col[base + lane] : 0;
#pragma unroll 2
        for (int u = 0; u < cnt; u += 4) {
            int eg = u + g;
            int s = __shfl(myCol, eg, 64);
            float e = asrc[s * 8 + head] + adv;
            e = (e > 0.f) ? e : LRELU * e;
            float w = (eg < cnt) ? __expf(e) : 0.f;
            uint2 hv = Hb4[(size_t)s * 16 + sub];
            denom += w;
            acc.x = fmaf(w, bf2f(hv.x & 0xffffu), acc.x);
            acc.y = fmaf(w, bf2f(hv.x >> 16), acc.y);
            acc.z = fmaf(w, bf2f(hv.y & 0xffffu), acc.z);
            acc.w = fmaf(w, bf2f(hv.y >> 16), acc.w);
        }
    }
#pragma unroll
    for (int off = 16; off < 64; off <<= 1) {
        acc.x += __shfl_xor(acc.x, off, 64);
        acc.y += __shfl_xor(acc.y, off, 64);
        acc.z += __shfl_xor(acc.z, off, 64);
        acc.w += __shfl_xor(acc.w, off, 64);
        denom += __shfl_xor(denom, off, 64);
    }
    if (lane < 16) {
        float invd = 1.f / (denom + 1e-16f);
        float4 b = bias4[sub];
        float4 v;
        v.x = fmaf(acc.x, invd, b.x);
        v.y = fmaf(acc.y, invd, b.y);
        v.z = fmaf(acc.z, invd, b.z);
        v.w = fmaf(acc.w, invd, b.w);
        v.x = (v.x > 0.f) ? v.x : expm1f(v.x);
        v.y = (v.y > 0.f) ? v.y : expm1f(v.y);
        v.z = (v.z > 0.f) ? v.z : expm1f(v.z);
        v.w = (v.w > 0.f) ? v.w : expm1f(v.w);
        uint2 pv;
        pv.x = (unsigned)f2bf(v.x) | ((unsigned)f2bf(v.y) << 16);
        pv.y = (unsigned)f2bf(v.z) | ((unsigned)f2bf(v.w) << 16);
        *reinterpret_cast<uint2*>(&outb[(size_t)d * 64 + sub * 4]) = pv;
    }
}

__global__ __launch_bounds__(256) void k_gather2(const int* __restrict__ rowptr,
                                                 const int* __restrict__ col,
                                                 const uint2* __restrict__ Gb4,
                                                 const float* __restrict__ asrc,
                                                 const float* __restrict__ adst,
                                                 const float4* __restrict__ bias4,
                                                 int N, float4* __restrict__ out4) {
    int lane = threadIdx.x & 63;
    int d = (blockIdx.x << 2) + (threadIdx.x >> 6);
    if (d >= N) return;
    int g = lane >> 4;
    int sub = lane & 15;
    float adv = adst[d];
    int jb = rowptr[d], je = rowptr[d + 1];

    float4 acc = {0.f, 0.f, 0.f, 0.f};
    float denom = 0.f;
    for (int base = jb; base < je; base += 64) {
        int cnt = je - base; if (cnt > 64) cnt = 64;
        int myCol = (lane < cnt) ? col[base + lane] : 0;
#pragma unroll 2
        for (int u = 0; u < cnt; u += 4) {
            int eg = u + g;
            int s = __shfl(myCol, eg, 64);
            float e = asrc[s] + adv;
            e = (e > 0.f) ? e : LRELU * e;
            float w = (eg < cnt) ? __expf(e) : 0.f;
            uint2 hv = Gb4[(size_t)s * 16 + sub];
            denom += w;
            acc.x = fmaf(w, bf2f(hv.x & 0xffffu), acc.x);
            acc.y = fmaf(w, bf2f(hv.x >> 16), acc.y);
            acc.z = fmaf(w, bf2f(hv.y & 0xffffu), acc.z);
            acc.w = fmaf(w, bf2f(hv.y >> 16), acc.w);
        }
    }
#pragma unroll
    for (int off = 16; off < 64; off <<= 1) {
        acc.x += __shfl_xor(acc.x, off, 64);
        acc.y += __shfl_xor(acc.y, off, 64);
        acc.z += __shfl_xor(acc.z, off, 64);
        acc.w += __shfl_xor(acc.w, off, 64);
        denom += __shfl_xor(denom, off, 64);
    }
    float invd = 1.f / (denom + 1e-16f);
    float4 b = bias4[sub];
    float4 v;
    v.x = fmaf(acc.x, invd, b.x);
    v.y = fmaf(acc.y, invd, b.y);
    v.z = fmaf(acc.z, invd, b.z);
    v.w = fmaf(acc.w, invd, b.w);
    float m = fmaxf(fmaxf(v.x, v.y), fmaxf(v.z, v.w));
#pragma unroll
    for (int off = 1; off < 16; off <<= 1) m = fmaxf(m, __shfl_xor(m, off, 64));
    float se = __expf(v.x - m) + __expf(v.y - m) + __expf(v.z - m) + __expf(v.w - m);
#pragma unroll
    for (int off = 1; off < 16; off <<= 1) se += __shfl_xor(se, off, 64);
    float ls = m + __logf(se);
    if (lane < 16) {
        v.x -= ls; v.y -= ls; v.z -= ls; v.w -= ls;
        out4[(size_t)d * 16 + sub] = v;
    }
}

// ---------------- launch ----------------

extern "C" void kernel_launch(void* const* d_in, const int* in_sizes, int n_in,
                              void* d_out, int out_size, void* d_ws, size_t ws_size,
                              hipStream_t stream) {
    const float* x   = (const float*)d_in[0];
    const int*   ei  = (const int*)d_in[1];
    const float* W1  = (const float*)d_in[2];
    const float* as1 = (const float*)d_in[3];
    const float* ad1 = (const float*)d_in[4];
    const float* b1  = (const float*)d_in[5];
    const float* W2  = (const float*)d_in[6];
    const float* as2 = (const float*)d_in[7];
    const float* ad2 = (const float*)d_in[8];
    const float* b2  = (const float*)d_in[9];
    float* out = (float*)d_out;

    const int N = in_sizes[0] / 256;
    const int E = in_sizes[1] / 2;
    const int* src = ei;
    const int* dst = ei + E;

    char* ws = (char*)d_ws;
    size_t off = 0;
    auto alloc = [&](size_t bytes) -> void* {
        void* p = ws + off;
        off = (off + bytes + 255) & ~(size_t)255;
        return p;
    };
    const int nb = (N + 1023) / 1024;
    int*   deg    = (int*)alloc((size_t)N * 4);
    int*   rowptr = (int*)alloc((size_t)(N + 1) * 4);
    int*   cursor = (int*)alloc((size_t)N * 4);
    int*   bsum   = (int*)alloc((size_t)nb * 4);
    int*   boff   = (int*)alloc((size_t)nb * 4);
    int*   col    = (int*)alloc((size_t)E * 4);
    unsigned short* wt1 = (unsigned short*)alloc(64 * 256 * 2);
    unsigned short* wt2 = (unsigned short*)alloc(64 * 64 * 2);
    unsigned short* h1b = (unsigned short*)alloc((size_t)N * 64 * 2);
    float* a_s1   = (float*)alloc((size_t)N * 8 * 4);
    float* a_d1   = (float*)alloc((size_t)N * 8 * 4);
    unsigned short* h2b = (unsigned short*)alloc((size_t)N * 64 * 2);
    unsigned short* gb  = (unsigned short*)alloc((size_t)N * 64 * 2);
    float* a_s2   = (float*)alloc((size_t)N * 4);
    float* a_d2   = (float*)alloc((size_t)N * 4);
    (void)ws_size; (void)n_in; (void)out_size;

    k_cvtW<<<80, 256, 0, stream>>>(W1, W2, wt1, wt2);

    hipMemsetAsync(deg, 0, (size_t)N * 4, stream);
    k_hist<<<2048, 256, 0, stream>>>(dst, E, deg);
    k_partsum<<<nb, 256, 0, stream>>>(deg, N, bsum);
    k_scansum<<<1, 64, 0, stream>>>(bsum, nb, boff, rowptr, N);
    k_scanwrite<<<nb, 256, 0, stream>>>(deg, N, boff, rowptr, cursor);
    k_scatter<<<2048, 256, 0, stream>>>(src, dst, E, cursor, col);

    int gblk = (N + 63) / 64;
    k_gemm1m<<<gblk, 256, 0, stream>>>(x, wt1, as1, ad1, N, h1b, a_s1, a_d1);

    int gather_blocks = (N + 3) / 4;
    k_gather1<<<gather_blocks, 256, 0, stream>>>(rowptr, col, (const uint2*)h1b,
                                                 a_s1, a_d1, (const float4*)b1, N, h2b);

    k_gemm2m<<<gblk, 256, 0, stream>>>(h2b, wt2, as2, ad2, N, gb, a_s2, a_d2);

    k_gather2<<<gather_blocks, 256, 0, stream>>>(rowptr, col, (const uint2*)gb,
                                                 a_s2, a_d2, (const float4*)b2, N,
                                                 (float4*)out);
}

// Round 5
// 367.294 us; speedup vs baseline: 2.3622x; 1.2128x over previous
//
#include <hip/hip_runtime.h>
#include <math.h>

#define LRELU 0.2f
#define BSH 7                  // 128 dsts per bucket
#define BSZ (1 << BSH)
#define CH 4096                // edges per phase-1 block

typedef __attribute__((ext_vector_type(8))) short bf16x8;
typedef __attribute__((ext_vector_type(4))) float f32x4;

static __device__ __forceinline__ float bf2f(unsigned int u16) {
    union { unsigned int i; float f; } c; c.i = u16 << 16; return c.f;
}
static __device__ __forceinline__ unsigned short f2bf(float f) {
    union { float f; unsigned int i; } c; c.f = f;
    unsigned int x = c.i;
    return (unsigned short)((x + 0x7fffu + ((x >> 16) & 1u)) >> 16);  // RNE
}

// ---------------- CSR build ----------------

__global__ void k_hist(const int* __restrict__ dst, int E, int* __restrict__ deg) {
    int i = blockIdx.x * blockDim.x + threadIdx.x;
    int stride = gridDim.x * blockDim.x;
    for (; i < E; i += stride) atomicAdd(&deg[dst[i]], 1);
}

__global__ __launch_bounds__(256) void k_partsum(const int* __restrict__ deg, int N,
                                                 int* __restrict__ bsum) {
    int t = threadIdx.x, lane = t & 63, wv = t >> 6;
    int base = blockIdx.x * 1024 + t * 4;
    int s = 0;
    if (base + 3 < N) {
        int4 v = *reinterpret_cast<const int4*>(deg + base);
        s = v.x + v.y + v.z + v.w;
    } else {
        for (int i = 0; i < 4; ++i) if (base + i < N) s += deg[base + i];
    }
#pragma unroll
    for (int off = 1; off < 64; off <<= 1) s += __shfl_xor(s, off, 64);
    __shared__ int ws[4];
    if (lane == 0) ws[wv] = s;
    __syncthreads();
    if (t == 0) bsum[blockIdx.x] = ws[0] + ws[1] + ws[2] + ws[3];
}

__global__ __launch_bounds__(64) void k_scansum(const int* __restrict__ bsum, int nb,
                                                int* __restrict__ boff,
                                                int* __restrict__ rowptr, int N) {
    int lane = threadIdx.x;
    int run = 0;
    for (int base = 0; base < nb; base += 64) {
        int v = (base + lane < nb) ? bsum[base + lane] : 0;
        int inc = v;
#pragma unroll
        for (int off = 1; off < 64; off <<= 1) {
            int t = __shfl_up(inc, off, 64);
            if (lane >= off) inc += t;
        }
        if (base + lane < nb) boff[base + lane] = run + inc - v;
        run += __shfl(inc, 63, 64);
    }
    if (lane == 0) rowptr[N] = run;
}

__global__ __launch_bounds__(256) void k_scanwrite(const int* __restrict__ deg, int N,
                                                   const int* __restrict__ boff,
                                                   int* __restrict__ rowptr) {
    int t = threadIdx.x, lane = t & 63, wv = t >> 6;
    int base = blockIdx.x * 1024 + t * 4;
    int v[4] = {0, 0, 0, 0};
    if (base + 3 < N) {
        int4 q = *reinterpret_cast<const int4*>(deg + base);
        v[0] = q.x; v[1] = q.y; v[2] = q.z; v[3] = q.w;
    } else {
        for (int i = 0; i < 4; ++i) if (base + i < N) v[i] = deg[base + i];
    }
    int s = v[0] + v[1] + v[2] + v[3];
    int inc = s;
#pragma unroll
    for (int off = 1; off < 64; off <<= 1) {
        int q = __shfl_up(inc, off, 64);
        if (lane >= off) inc += q;
    }
    __shared__ int wtot[4];
    if (lane == 63) wtot[wv] = inc;
    __syncthreads();
    int woff = 0;
    for (int w = 0; w < wv; ++w) woff += wtot[w];
    int excl = woff + inc - s + boff[blockIdx.x];
    for (int i = 0; i < 4; ++i) {
        if (base + i < N) {
            rowptr[base + i] = excl;
            excl += v[i];
        }
    }
}

__global__ void k_bcur(const int* __restrict__ rowptr, int N, int NB,
                       int* __restrict__ bcur) {
    int b = blockIdx.x * blockDim.x + threadIdx.x;
    if (b < NB) {
        int d = b << BSH; if (d > N) d = N;
        bcur[b] = rowptr[d];
    }
}

// Phase 1: bin edges by dst bucket into per-bucket runs of (src,dst) pairs.
__global__ __launch_bounds__(256) void k_binscat1(const int* __restrict__ src,
                                                  const int* __restrict__ dst,
                                                  int E, int NB,
                                                  int* __restrict__ bcur,
                                                  int2* __restrict__ pairs) {
    __shared__ int cnt[512];
    __shared__ int lds_dst[CH];
    int t = threadIdx.x;
    int e0 = blockIdx.x * CH;
    for (int b = t; b < NB; b += 256) cnt[b] = 0;
    __syncthreads();
    for (int i = t; i < CH; i += 256) {
        int e = e0 + i;
        int d = (e < E) ? dst[e] : -1;
        lds_dst[i] = d;
        if (d >= 0) atomicAdd(&cnt[d >> BSH], 1);
    }
    __syncthreads();
    for (int b = t; b < NB; b += 256) {
        int c = cnt[b];
        cnt[b] = (c > 0) ? atomicAdd(&bcur[b], c) : 0;
    }
    __syncthreads();
    for (int i = t; i < CH; i += 256) {
        int e = e0 + i;
        if (e < E) {
            int d = lds_dst[i];
            int p = atomicAdd(&cnt[d >> BSH], 1);
            int2 pr; pr.x = src[e]; pr.y = d;
            pairs[p] = pr;
        }
    }
}

// Phase 2: within each bucket, place srcs at exact CSR positions (LDS cursors).
__global__ __launch_bounds__(256) void k_binscat2(const int* __restrict__ rowptr,
                                                  const int2* __restrict__ pairs,
                                                  int N, int* __restrict__ col) {
    __shared__ int cur[BSZ];
    int t = threadIdx.x;
    int dlo = blockIdx.x << BSH;
    int dhi = dlo + BSZ; if (dhi > N) dhi = N;
    if (t < dhi - dlo) cur[t] = rowptr[dlo + t];
    __syncthreads();
    int jb = rowptr[dlo], je = rowptr[dhi];
    for (int j = jb + t; j < je; j += 256) {
        int2 pr = pairs[j];
        int p = atomicAdd(&cur[pr.y - dlo], 1);
        col[p] = pr.x;
    }
}

// ---------------- weight convert/transpose to bf16 ----------------
__global__ __launch_bounds__(256) void k_cvtW(const float* __restrict__ W1,
                                              const float* __restrict__ W2,
                                              unsigned short* __restrict__ Wt1,
                                              unsigned short* __restrict__ Wt2) {
    int idx = blockIdx.x * 256 + threadIdx.x;
    if (idx < 16384) {
        int n = idx >> 8, k = idx & 255;
        Wt1[idx] = f2bf(W1[k * 64 + n]);
    } else if (idx < 16384 + 4096) {
        int j = idx - 16384;
        int n = j >> 6, k = j & 63;
        Wt2[j] = f2bf(W2[k * 64 + n]);
    }
}

// ---------------- MFMA GEMM1 ----------------
__global__ __launch_bounds__(256) void k_gemm1m(const float* __restrict__ X,
                                                const unsigned short* __restrict__ Wt,
                                                const float* __restrict__ atts,
                                                const float* __restrict__ attd,
                                                int N, unsigned short* __restrict__ Hb,
                                                float* __restrict__ asrc,
                                                float* __restrict__ adst) {
    __shared__ short Xl[64 * 256];
    int t = threadIdx.x, l = t & 63, w = t >> 6;
    int rblk = blockIdx.x * 64;

    int half = l >> 5;
    int c8 = (l & 31) * 8;
#pragma unroll
    for (int i = 0; i < 8; ++i) {
        int rl = w * 16 + i * 2 + half;
        int row = rblk + rl;
        float4 x0 = {0.f, 0.f, 0.f, 0.f}, x1 = {0.f, 0.f, 0.f, 0.f};
        if (row < N) {
            x0 = *reinterpret_cast<const float4*>(X + (size_t)row * 256 + c8);
            x1 = *reinterpret_cast<const float4*>(X + (size_t)row * 256 + c8 + 4);
        }
        bf16x8 p;
        p[0] = (short)f2bf(x0.x); p[1] = (short)f2bf(x0.y);
        p[2] = (short)f2bf(x0.z); p[3] = (short)f2bf(x0.w);
        p[4] = (short)f2bf(x1.x); p[5] = (short)f2bf(x1.y);
        p[6] = (short)f2bf(x1.z); p[7] = (short)f2bf(x1.w);
        int g = (l & 31) ^ (rl & 7);
        *reinterpret_cast<bf16x8*>(&Xl[rl * 256 + g * 8]) = p;
    }

    int m = l & 15, quad = l >> 4;
    int rl = w * 16 + m;
    f32x4 acc0 = {0.f, 0.f, 0.f, 0.f}, acc1 = acc0, acc2 = acc0, acc3 = acc0;
#pragma unroll
    for (int tt = 0; tt < 8; ++tt) {
        int g = (tt * 4 + quad) ^ (m & 7);
        bf16x8 a = *reinterpret_cast<const bf16x8*>(&Xl[rl * 256 + g * 8]);
        int kk = tt * 32 + quad * 8;
        bf16x8 b0 = *reinterpret_cast<const bf16x8*>(&Wt[(0 * 16 + m) * 256 + kk]);
        bf16x8 b1 = *reinterpret_cast<const bf16x8*>(&Wt[(1 * 16 + m) * 256 + kk]);
        bf16x8 b2 = *reinterpret_cast<const bf16x8*>(&Wt[(2 * 16 + m) * 256 + kk]);
        bf16x8 b3 = *reinterpret_cast<const bf16x8*>(&Wt[(3 * 16 + m) * 256 + kk]);
        acc0 = __builtin_amdgcn_mfma_f32_16x16x32_bf16(a, b0, acc0, 0, 0, 0);
        acc1 = __builtin_amdgcn_mfma_f32_16x16x32_bf16(a, b1, acc1, 0, 0, 0);
        acc2 = __builtin_amdgcn_mfma_f32_16x16x32_bf16(a, b2, acc2, 0, 0, 0);
        acc3 = __builtin_amdgcn_mfma_f32_16x16x32_bf16(a, b3, acc3, 0, 0, 0);
    }

    int r0 = rblk + w * 16;
    f32x4 accs[4] = {acc0, acc1, acc2, acc3};
#pragma unroll
    for (int nt = 0; nt < 4; ++nt) {
        int cn = nt * 16 + m;
        float av_s = atts[cn], av_d = attd[cn];
#pragma unroll
        for (int r = 0; r < 4; ++r) {
            int row = r0 + quad * 4 + r;
            float hv = accs[nt][r];
            if (row < N) Hb[(size_t)row * 64 + cn] = f2bf(hv);
            float vs = hv * av_s, vd = hv * av_d;
            vs += __shfl_xor(vs, 1, 64); vs += __shfl_xor(vs, 2, 64); vs += __shfl_xor(vs, 4, 64);
            vd += __shfl_xor(vd, 1, 64); vd += __shfl_xor(vd, 2, 64); vd += __shfl_xor(vd, 4, 64);
            if ((m & 7) == 0 && row < N) {
                int head = cn >> 3;
                asrc[row * 8 + head] = vs;
                adst[row * 8 + head] = vd;
            }
        }
    }
}

// ---------------- MFMA GEMM2 ----------------
__global__ __launch_bounds__(256) void k_gemm2m(const unsigned short* __restrict__ Xb,
                                                const unsigned short* __restrict__ Wt,
                                                const float* __restrict__ atts,
                                                const float* __restrict__ attd,
                                                int N, unsigned short* __restrict__ Gb,
                                                float* __restrict__ asrc,
                                                float* __restrict__ adst) {
    int t = threadIdx.x, l = t & 63, w = t >> 6;
    int rblk = blockIdx.x * 64;
    int m = l & 15, quad = l >> 4;
    int row = rblk + w * 16 + m;
    int rowc = (row < N) ? row : 0;

    f32x4 acc0 = {0.f, 0.f, 0.f, 0.f}, acc1 = acc0, acc2 = acc0, acc3 = acc0;
#pragma unroll
    for (int tt = 0; tt < 2; ++tt) {
        int kk = tt * 32 + quad * 8;
        bf16x8 a = *reinterpret_cast<const bf16x8*>(&Xb[(size_t)rowc * 64 + kk]);
        bf16x8 b0 = *reinterpret_cast<const bf16x8*>(&Wt[(0 * 16 + m) * 64 + kk]);
        bf16x8 b1 = *reinterpret_cast<const bf16x8*>(&Wt[(1 * 16 + m) * 64 + kk]);
        bf16x8 b2 = *reinterpret_cast<const bf16x8*>(&Wt[(2 * 16 + m) * 64 + kk]);
        bf16x8 b3 = *reinterpret_cast<const bf16x8*>(&Wt[(3 * 16 + m) * 64 + kk]);
        acc0 = __builtin_amdgcn_mfma_f32_16x16x32_bf16(a, b0, acc0, 0, 0, 0);
        acc1 = __builtin_amdgcn_mfma_f32_16x16x32_bf16(a, b1, acc1, 0, 0, 0);
        acc2 = __builtin_amdgcn_mfma_f32_16x16x32_bf16(a, b2, acc2, 0, 0, 0);
        acc3 = __builtin_amdgcn_mfma_f32_16x16x32_bf16(a, b3, acc3, 0, 0, 0);
    }

    int r0 = rblk + w * 16;
    f32x4 accs[4] = {acc0, acc1, acc2, acc3};
#pragma unroll
    for (int r = 0; r < 4; ++r) {
        int orow = r0 + quad * 4 + r;
        float vs = 0.f, vd = 0.f;
#pragma unroll
        for (int nt = 0; nt < 4; ++nt) {
            int cn = nt * 16 + m;
            float hv = accs[nt][r];
            if (orow < N) Gb[(size_t)orow * 64 + cn] = f2bf(hv);
            vs = fmaf(hv, atts[cn], vs);
            vd = fmaf(hv, attd[cn], vd);
        }
#pragma unroll
        for (int off = 1; off < 16; off <<= 1) {
            vs += __shfl_xor(vs, off, 64);
            vd += __shfl_xor(vd, off, 64);
        }
        if (m == 0 && orow < N) { asrc[orow] = vs; adst[orow] = vd; }
    }
}

// ---------------- Fused per-dst gather, 4 edges in flight ----------------

__global__ __launch_bounds__(256) void k_gather1(const int* __restrict__ rowptr,
                                                 const int* __restrict__ col,
                                                 const uint2* __restrict__ Hb4,
                                                 const float* __restrict__ asrc,
                                                 const float* __restrict__ adst,
                                                 const float4* __restrict__ bias4,
                                                 int N, unsigned short* __restrict__ outb) {
    int lane = threadIdx.x & 63;
    int d = (blockIdx.x << 2) + (threadIdx.x >> 6);
    if (d >= N) return;
    int g = lane >> 4;
    int sub = lane & 15;
    int head = sub >> 1;
    float adv = adst[d * 8 + head];
    int jb = rowptr[d], je = rowptr[d + 1];

    float4 acc = {0.f, 0.f, 0.f, 0.f};
    float denom = 0.f;
    for (int base = jb; base < je; base += 64) {
        int cnt = je - base; if (cnt > 64) cnt = 64;
        int myCol = (lane < cnt) ? col[base + lane] : 0;
#pragma unroll 2
        for (int u = 0; u < cnt; u += 4) {
            int eg = u + g;
            int s = __shfl(myCol, eg, 64);
            float e = asrc[s * 8 + head] + adv;
            e = (e > 0.f) ? e : LRELU * e;
            float w = (eg < cnt) ? __expf(e) : 0.f;
            uint2 hv = Hb4[(size_t)s * 16 + sub];
            denom += w;
            acc.x = fmaf(w, bf2f(hv.x & 0xffffu), acc.x);
            acc.y = fmaf(w, bf2f(hv.x >> 16), acc.y);
            acc.z = fmaf(w, bf2f(hv.y & 0xffffu), acc.z);
            acc.w = fmaf(w, bf2f(hv.y >> 16), acc.w);
        }
    }
#pragma unroll
    for (int off = 16; off < 64; off <<= 1) {
        acc.x += __shfl_xor(acc.x, off, 64);
        acc.y += __shfl_xor(acc.y, off, 64);
        acc.z += __shfl_xor(acc.z, off, 64);
        acc.w += __shfl_xor(acc.w, off, 64);
        denom += __shfl_xor(denom, off, 64);
    }
    if (lane < 16) {
        float invd = 1.f / (denom + 1e-16f);
        float4 b = bias4[sub];
        float4 v;
        v.x = fmaf(acc.x, invd, b.x);
        v.y = fmaf(acc.y, invd, b.y);
        v.z = fmaf(acc.z, invd, b.z);
        v.w = fmaf(acc.w, invd, b.w);
        v.x = (v.x > 0.f) ? v.x : expm1f(v.x);
        v.y = (v.y > 0.f) ? v.y : expm1f(v.y);
        v.z = (v.z > 0.f) ? v.z : expm1f(v.z);
        v.w = (v.w > 0.f) ? v.w : expm1f(v.w);
        uint2 pv;
        pv.x = (unsigned)f2bf(v.x) | ((unsigned)f2bf(v.y) << 16);
        pv.y = (unsigned)f2bf(v.z) | ((unsigned)f2bf(v.w) << 16);
        *reinterpret_cast<uint2*>(&outb[(size_t)d * 64 + sub * 4]) = pv;
    }
}

__global__ __launch_bounds__(256) void k_gather2(const int* __restrict__ rowptr,
                                                 const int* __restrict__ col,
                                                 const uint2* __restrict__ Gb4,
                                                 const float* __restrict__ asrc,
                                                 const float* __restrict__ adst,
                                                 const float4* __restrict__ bias4,
                                                 int N, float4* __restrict__ out4) {
    int lane = threadIdx.x & 63;
    int d = (blockIdx.x << 2) + (threadIdx.x >> 6);
    if (d >= N) return;
    int g = lane >> 4;
    int sub = lane & 15;
    float adv = adst[d];
    int jb = rowptr[d], je = rowptr[d + 1];

    float4 acc = {0.f, 0.f, 0.f, 0.f};
    float denom = 0.f;
    for (int base = jb; base < je; base += 64) {
        int cnt = je - base; if (cnt > 64) cnt = 64;
        int myCol = (lane < cnt) ? col[base + lane] : 0;
#pragma unroll 2
        for (int u = 0; u < cnt; u += 4) {
            int eg = u + g;
            int s = __shfl(myCol, eg, 64);
            float e = asrc[s] + adv;
            e = (e > 0.f) ? e : LRELU * e;
            float w = (eg < cnt) ? __expf(e) : 0.f;
            uint2 hv = Gb4[(size_t)s * 16 + sub];
            denom += w;
            acc.x = fmaf(w, bf2f(hv.x & 0xffffu), acc.x);
            acc.y = fmaf(w, bf2f(hv.x >> 16), acc.y);
            acc.z = fmaf(w, bf2f(hv.y & 0xffffu), acc.z);
            acc.w = fmaf(w, bf2f(hv.y >> 16), acc.w);
        }
    }
#pragma unroll
    for (int off = 16; off < 64; off <<= 1) {
        acc.x += __shfl_xor(acc.x, off, 64);
        acc.y += __shfl_xor(acc.y, off, 64);
        acc.z += __shfl_xor(acc.z, off, 64);
        acc.w += __shfl_xor(acc.w, off, 64);
        denom += __shfl_xor(denom, off, 64);
    }
    float invd = 1.f / (denom + 1e-16f);
    float4 b = bias4[sub];
    float4 v;
    v.x = fmaf(acc.x, invd, b.x);
    v.y = fmaf(acc.y, invd, b.y);
    v.z = fmaf(acc.z, invd, b.z);
    v.w = fmaf(acc.w, invd, b.w);
    float m = fmaxf(fmaxf(v.x, v.y), fmaxf(v.z, v.w));
#pragma unroll
    for (int off = 1; off < 16; off <<= 1) m = fmaxf(m, __shfl_xor(m, off, 64));
    float se = __expf(v.x - m) + __expf(v.y - m) + __expf(v.z - m) + __expf(v.w - m);
#pragma unroll
    for (int off = 1; off < 16; off <<= 1) se += __shfl_xor(se, off, 64);
    float ls = m + __logf(se);
    if (lane < 16) {
        v.x -= ls; v.y -= ls; v.z -= ls; v.w -= ls;
        out4[(size_t)d * 16 + sub] = v;
    }
}

// ---------------- launch ----------------

extern "C" void kernel_launch(void* const* d_in, const int* in_sizes, int n_in,
                              void* d_out, int out_size, void* d_ws, size_t ws_size,
                              hipStream_t stream) {
    const float* x   = (const float*)d_in[0];
    const int*   ei  = (const int*)d_in[1];
    const float* W1  = (const float*)d_in[2];
    const float* as1 = (const float*)d_in[3];
    const float* ad1 = (const float*)d_in[4];
    const float* b1  = (const float*)d_in[5];
    const float* W2  = (const float*)d_in[6];
    const float* as2 = (const float*)d_in[7];
    const float* ad2 = (const float*)d_in[8];
    const float* b2  = (const float*)d_in[9];
    float* out = (float*)d_out;

    const int N = in_sizes[0] / 256;
    const int E = in_sizes[1] / 2;
    const int* src = ei;
    const int* dst = ei + E;
    const int NB = (N + BSZ - 1) >> BSH;

    char* ws = (char*)d_ws;
    size_t off = 0;
    auto alloc = [&](size_t bytes) -> void* {
        void* p = ws + off;
        off = (off + bytes + 255) & ~(size_t)255;
        return p;
    };
    const int nb = (N + 1023) / 1024;
    int*   deg    = (int*)alloc((size_t)N * 4);
    int*   rowptr = (int*)alloc((size_t)(N + 1) * 4);
    int*   bcur   = (int*)alloc((size_t)NB * 4);
    int*   bsum   = (int*)alloc((size_t)nb * 4);
    int*   boff   = (int*)alloc((size_t)nb * 4);
    int*   col    = (int*)alloc((size_t)E * 4);
    int2*  pairs  = (int2*)alloc((size_t)E * 8);
    unsigned short* wt1 = (unsigned short*)alloc(64 * 256 * 2);
    unsigned short* wt2 = (unsigned short*)alloc(64 * 64 * 2);
    unsigned short* h1b = (unsigned short*)alloc((size_t)N * 64 * 2);
    float* a_s1   = (float*)alloc((size_t)N * 8 * 4);
    float* a_d1   = (float*)alloc((size_t)N * 8 * 4);
    unsigned short* h2b = (unsigned short*)alloc((size_t)N * 64 * 2);
    unsigned short* gb  = (unsigned short*)alloc((size_t)N * 64 * 2);
    float* a_s2   = (float*)alloc((size_t)N * 4);
    float* a_d2   = (float*)alloc((size_t)N * 4);
    (void)ws_size; (void)n_in; (void)out_size;

    k_cvtW<<<80, 256, 0, stream>>>(W1, W2, wt1, wt2);

    hipMemsetAsync(deg, 0, (size_t)N * 4, stream);
    k_hist<<<2048, 256, 0, stream>>>(dst, E, deg);
    k_partsum<<<nb, 256, 0, stream>>>(deg, N, bsum);
    k_scansum<<<1, 64, 0, stream>>>(bsum, nb, boff, rowptr, N);
    k_scanwrite<<<nb, 256, 0, stream>>>(deg, N, boff, rowptr);
    k_bcur<<<(NB + 255) / 256, 256, 0, stream>>>(rowptr, N, NB, bcur);
    k_binscat1<<<(E + CH - 1) / CH, 256, 0, stream>>>(src, dst, E, NB, bcur, pairs);
    k_binscat2<<<NB, 256, 0, stream>>>(rowptr, pairs, N, col);

    int gblk = (N + 63) / 64;
    k_gemm1m<<<gblk, 256, 0, stream>>>(x, wt1, as1, ad1, N, h1b, a_s1, a_d1);

    int gather_blocks = (N + 3) / 4;
    k_gather1<<<gather_blocks, 256, 0, stream>>>(rowptr, col, (const uint2*)h1b,
                                                 a_s1, a_d1, (const float4*)b1, N, h2b);

    k_gemm2m<<<gblk, 256, 0, stream>>>(h2b, wt2, as2, ad2, N, gb, a_s2, a_d2);

    k_gather2<<<gather_blocks, 256, 0, stream>>>(rowptr, col, (const uint2*)gb,
                                                 a_s2, a_d2, (const float4*)b2, N,
                                                 (float4*)out);
}

// Round 6
// 308.726 us; speedup vs baseline: 2.8103x; 1.1897x over previous
//
#include <hip/hip_runtime.h>
#include <math.h>

#define LRELU 0.2f
#define BSH 7                  // 128 dsts per bucket
#define BSZ (1 << BSH)
#define CH 8192                // edges per phase-1 block

typedef __attribute__((ext_vector_type(8))) short bf16x8;
typedef __attribute__((ext_vector_type(4))) float f32x4;

static __device__ __forceinline__ float bf2f(unsigned int u16) {
    union { unsigned int i; float f; } c; c.i = u16 << 16; return c.f;
}
static __device__ __forceinline__ unsigned short f2bf(float f) {
    union { float f; unsigned int i; } c; c.f = f;
    unsigned int x = c.i;
    return (unsigned short)((x + 0x7fffu + ((x >> 16) & 1u)) >> 16);  // RNE
}

// ---------------- CSR build (bucket-centric, no N-wide histogram) ----------

// Count edges per 128-dst bucket. LDS-aggregated; ~NB global atomics/block.
__global__ __launch_bounds__(256) void k_bcount(const int* __restrict__ dst, int E,
                                                int NB, int* __restrict__ bcnt) {
    __shared__ int cnt[512];
    int t = threadIdx.x;
    for (int b = t; b < 512; b += 256) cnt[b] = 0;
    __syncthreads();
    int e0 = blockIdx.x * CH;
    int e1 = e0 + CH; if (e1 > E) e1 = E;
    for (int i = e0 + t; i < e1; i += 256) atomicAdd(&cnt[dst[i] >> BSH], 1);
    __syncthreads();
    for (int b = t; b < NB; b += 256) {
        int c = cnt[b];
        if (c) atomicAdd(&bcnt[b], c);
    }
}

// Single-wave scan of bucket counts -> run offsets (boff) + mutable copy (bcur).
__global__ __launch_bounds__(64) void k_bscan(const int* __restrict__ bcnt, int NB,
                                              int* __restrict__ boff,
                                              int* __restrict__ bcur) {
    int lane = threadIdx.x;
    int run = 0;
    for (int base = 0; base < NB; base += 64) {
        int v = (base + lane < NB) ? bcnt[base + lane] : 0;
        int inc = v;
#pragma unroll
        for (int off = 1; off < 64; off <<= 1) {
            int t = __shfl_up(inc, off, 64);
            if (lane >= off) inc += t;
        }
        if (base + lane < NB) {
            int e = run + inc - v;
            boff[base + lane] = e;
            bcur[base + lane] = e;
        }
        run += __shfl(inc, 63, 64);
    }
    if (lane == 0) boff[NB] = run;
}

// Phase 1: bin edges into per-bucket runs of packed (src<<7)|dloc words.
__global__ __launch_bounds__(256) void k_binscat1(const int* __restrict__ src,
                                                  const int* __restrict__ dst,
                                                  int E, int NB,
                                                  int* __restrict__ bcur,
                                                  unsigned* __restrict__ pairs) {
    __shared__ int cnt[512];
    __shared__ int lds_d[CH];
    int t = threadIdx.x;
    int e0 = blockIdx.x * CH;
    int e1 = e0 + CH; if (e1 > E) e1 = E;
    int n = e1 - e0;
    for (int b = t; b < 512; b += 256) cnt[b] = 0;
    __syncthreads();
    for (int i = t; i < n; i += 256) {
        int d = dst[e0 + i];
        lds_d[i] = d;
        atomicAdd(&cnt[d >> BSH], 1);
    }
    __syncthreads();
    for (int b = t; b < NB; b += 256) {
        int c = cnt[b];
        cnt[b] = c ? atomicAdd(&bcur[b], c) : 0;
    }
    __syncthreads();
    for (int i = t; i < n; i += 256) {
        int d = lds_d[i];
        int p = atomicAdd(&cnt[d >> BSH], 1);
        pairs[p] = ((unsigned)src[e0 + i] << BSH) | (unsigned)(d & (BSZ - 1));
    }
}

// Phase 2: per bucket — local histogram + scan -> rowptr segment, place col.
__global__ __launch_bounds__(256) void k_bucket(const int* __restrict__ boff,
                                                const unsigned* __restrict__ pairs,
                                                int N, int* __restrict__ rowptr,
                                                int* __restrict__ col) {
    __shared__ int cnt[BSZ];
    __shared__ int cur[BSZ];
    int t = threadIdx.x;
    int b = blockIdx.x;
    int dlo = b << BSH;
    int dhi = dlo + BSZ; if (dhi > N) dhi = N;
    int nd = dhi - dlo;
    int jb = boff[b], je = boff[b + 1];
    if (t < BSZ) cnt[t] = 0;
    __syncthreads();
    for (int j = jb + t; j < je; j += 256) atomicAdd(&cnt[pairs[j] & (BSZ - 1)], 1);
    __syncthreads();
    if (t < 64) {
        int v0 = cnt[t], v1 = cnt[64 + t];
        int i0 = v0;
#pragma unroll
        for (int off = 1; off < 64; off <<= 1) {
            int q = __shfl_up(i0, off, 64);
            if (t >= off) i0 += q;
        }
        int tot0 = __shfl(i0, 63, 64);
        int i1 = v1;
#pragma unroll
        for (int off = 1; off < 64; off <<= 1) {
            int q = __shfl_up(i1, off, 64);
            if (t >= off) i1 += q;
        }
        int e0x = jb + i0 - v0;
        int e1x = jb + tot0 + i1 - v1;
        cur[t] = e0x;
        cur[64 + t] = e1x;
        if (t < nd) rowptr[dlo + t] = e0x;
        if (64 + t < nd) rowptr[dlo + 64 + t] = e1x;
        if (t == 0 && dhi == N) rowptr[N] = je;
    }
    __syncthreads();
    for (int j = jb + t; j < je; j += 256) {
        unsigned pk = pairs[j];
        int p = atomicAdd(&cur[pk & (BSZ - 1)], 1);
        col[p] = (int)(pk >> BSH);
    }
}

// ---------------- weight convert/transpose to bf16 ----------------
__global__ __launch_bounds__(256) void k_cvtW(const float* __restrict__ W1,
                                              const float* __restrict__ W2,
                                              unsigned short* __restrict__ Wt1,
                                              unsigned short* __restrict__ Wt2) {
    int idx = blockIdx.x * 256 + threadIdx.x;
    if (idx < 16384) {
        int n = idx >> 8, k = idx & 255;
        Wt1[idx] = f2bf(W1[k * 64 + n]);
    } else if (idx < 16384 + 4096) {
        int j = idx - 16384;
        int n = j >> 6, k = j & 63;
        Wt2[j] = f2bf(W2[k * 64 + n]);
    }
}

// ---------------- MFMA GEMM1 ----------------
__global__ __launch_bounds__(256) void k_gemm1m(const float* __restrict__ X,
                                                const unsigned short* __restrict__ Wt,
                                                const float* __restrict__ atts,
                                                const float* __restrict__ attd,
                                                int N, unsigned short* __restrict__ Hb,
                                                float* __restrict__ asrc,
                                                float* __restrict__ adst) {
    __shared__ short Xl[64 * 256];
    int t = threadIdx.x, l = t & 63, w = t >> 6;
    int rblk = blockIdx.x * 64;

    int half = l >> 5;
    int c8 = (l & 31) * 8;
#pragma unroll
    for (int i = 0; i < 8; ++i) {
        int rl = w * 16 + i * 2 + half;
        int row = rblk + rl;
        float4 x0 = {0.f, 0.f, 0.f, 0.f}, x1 = {0.f, 0.f, 0.f, 0.f};
        if (row < N) {
            x0 = *reinterpret_cast<const float4*>(X + (size_t)row * 256 + c8);
            x1 = *reinterpret_cast<const float4*>(X + (size_t)row * 256 + c8 + 4);
        }
        bf16x8 p;
        p[0] = (short)f2bf(x0.x); p[1] = (short)f2bf(x0.y);
        p[2] = (short)f2bf(x0.z); p[3] = (short)f2bf(x0.w);
        p[4] = (short)f2bf(x1.x); p[5] = (short)f2bf(x1.y);
        p[6] = (short)f2bf(x1.z); p[7] = (short)f2bf(x1.w);
        int g = (l & 31) ^ (rl & 7);
        *reinterpret_cast<bf16x8*>(&Xl[rl * 256 + g * 8]) = p;
    }

    int m = l & 15, quad = l >> 4;
    int rl = w * 16 + m;
    f32x4 acc0 = {0.f, 0.f, 0.f, 0.f}, acc1 = acc0, acc2 = acc0, acc3 = acc0;
#pragma unroll
    for (int tt = 0; tt < 8; ++tt) {
        int g = (tt * 4 + quad) ^ (m & 7);
        bf16x8 a = *reinterpret_cast<const bf16x8*>(&Xl[rl * 256 + g * 8]);
        int kk = tt * 32 + quad * 8;
        bf16x8 b0 = *reinterpret_cast<const bf16x8*>(&Wt[(0 * 16 + m) * 256 + kk]);
        bf16x8 b1 = *reinterpret_cast<const bf16x8*>(&Wt[(1 * 16 + m) * 256 + kk]);
        bf16x8 b2 = *reinterpret_cast<const bf16x8*>(&Wt[(2 * 16 + m) * 256 + kk]);
        bf16x8 b3 = *reinterpret_cast<const bf16x8*>(&Wt[(3 * 16 + m) * 256 + kk]);
        acc0 = __builtin_amdgcn_mfma_f32_16x16x32_bf16(a, b0, acc0, 0, 0, 0);
        acc1 = __builtin_amdgcn_mfma_f32_16x16x32_bf16(a, b1, acc1, 0, 0, 0);
        acc2 = __builtin_amdgcn_mfma_f32_16x16x32_bf16(a, b2, acc2, 0, 0, 0);
        acc3 = __builtin_amdgcn_mfma_f32_16x16x32_bf16(a, b3, acc3, 0, 0, 0);
    }

    int r0 = rblk + w * 16;
    f32x4 accs[4] = {acc0, acc1, acc2, acc3};
#pragma unroll
    for (int nt = 0; nt < 4; ++nt) {
        int cn = nt * 16 + m;
        float av_s = atts[cn], av_d = attd[cn];
#pragma unroll
        for (int r = 0; r < 4; ++r) {
            int row = r0 + quad * 4 + r;
            float hv = accs[nt][r];
            if (row < N) Hb[(size_t)row * 64 + cn] = f2bf(hv);
            float vs = hv * av_s, vd = hv * av_d;
            vs += __shfl_xor(vs, 1, 64); vs += __shfl_xor(vs, 2, 64); vs += __shfl_xor(vs, 4, 64);
            vd += __shfl_xor(vd, 1, 64); vd += __shfl_xor(vd, 2, 64); vd += __shfl_xor(vd, 4, 64);
            if ((m & 7) == 0 && row < N) {
                int head = cn >> 3;
                asrc[row * 8 + head] = vs;
                adst[row * 8 + head] = vd;
            }
        }
    }
}

// ---------------- MFMA GEMM2 ----------------
__global__ __launch_bounds__(256) void k_gemm2m(const unsigned short* __restrict__ Xb,
                                                const unsigned short* __restrict__ Wt,
                                                const float* __restrict__ atts,
                                                const float* __restrict__ attd,
                                                int N, unsigned short* __restrict__ Gb,
                                                float* __restrict__ asrc,
                                                float* __restrict__ adst) {
    int t = threadIdx.x, l = t & 63, w = t >> 6;
    int rblk = blockIdx.x * 64;
    int m = l & 15, quad = l >> 4;
    int row = rblk + w * 16 + m;
    int rowc = (row < N) ? row : 0;

    f32x4 acc0 = {0.f, 0.f, 0.f, 0.f}, acc1 = acc0, acc2 = acc0, acc3 = acc0;
#pragma unroll
    for (int tt = 0; tt < 2; ++tt) {
        int kk = tt * 32 + quad * 8;
        bf16x8 a = *reinterpret_cast<const bf16x8*>(&Xb[(size_t)rowc * 64 + kk]);
        bf16x8 b0 = *reinterpret_cast<const bf16x8*>(&Wt[(0 * 16 + m) * 64 + kk]);
        bf16x8 b1 = *reinterpret_cast<const bf16x8*>(&Wt[(1 * 16 + m) * 64 + kk]);
        bf16x8 b2 = *reinterpret_cast<const bf16x8*>(&Wt[(2 * 16 + m) * 64 + kk]);
        bf16x8 b3 = *reinterpret_cast<const bf16x8*>(&Wt[(3 * 16 + m) * 64 + kk]);
        acc0 = __builtin_amdgcn_mfma_f32_16x16x32_bf16(a, b0, acc0, 0, 0, 0);
        acc1 = __builtin_amdgcn_mfma_f32_16x16x32_bf16(a, b1, acc1, 0, 0, 0);
        acc2 = __builtin_amdgcn_mfma_f32_16x16x32_bf16(a, b2, acc2, 0, 0, 0);
        acc3 = __builtin_amdgcn_mfma_f32_16x16x32_bf16(a, b3, acc3, 0, 0, 0);
    }

    int r0 = rblk + w * 16;
    f32x4 accs[4] = {acc0, acc1, acc2, acc3};
#pragma unroll
    for (int r = 0; r < 4; ++r) {
        int orow = r0 + quad * 4 + r;
        float vs = 0.f, vd = 0.f;
#pragma unroll
        for (int nt = 0; nt < 4; ++nt) {
            int cn = nt * 16 + m;
            float hv = accs[nt][r];
            if (orow < N) Gb[(size_t)orow * 64 + cn] = f2bf(hv);
            vs = fmaf(hv, atts[cn], vs);
            vd = fmaf(hv, attd[cn], vd);
        }
#pragma unroll
        for (int off = 1; off < 16; off <<= 1) {
            vs += __shfl_xor(vs, off, 64);
            vd += __shfl_xor(vd, off, 64);
        }
        if (m == 0 && orow < N) { asrc[orow] = vs; adst[orow] = vd; }
    }
}

// ---------------- Fused per-dst gather, 4 edges in flight ----------------

__global__ __launch_bounds__(256) void k_gather1(const int* __restrict__ rowptr,
                                                 const int* __restrict__ col,
                                                 const uint2* __restrict__ Hb4,
                                                 const float* __restrict__ asrc,
                                                 const float* __restrict__ adst,
                                                 const float4* __restrict__ bias4,
                                                 int N, unsigned short* __restrict__ outb) {
    int lane = threadIdx.x & 63;
    int d = (blockIdx.x << 2) + (threadIdx.x >> 6);
    if (d >= N) return;
    int g = lane >> 4;
    int sub = lane & 15;
    int head = sub >> 1;
    float adv = adst[d * 8 + head];
    int jb = rowptr[d], je = rowptr[d + 1];

    float4 acc = {0.f, 0.f, 0.f, 0.f};
    float denom = 0.f;
    for (int base = jb; base < je; base += 64) {
        int cnt = je - base; if (cnt > 64) cnt = 64;
        int myCol = (lane < cnt) ? col[base + lane] : 0;
#pragma unroll 2
        for (int u = 0; u < cnt; u += 4) {
            int eg = u + g;
            int s = __shfl(myCol, eg, 64);
            float e = asrc[s * 8 + head] + adv;
            e = (e > 0.f) ? e : LRELU * e;
            float w = (eg < cnt) ? __expf(e) : 0.f;
            uint2 hv = Hb4[(size_t)s * 16 + sub];
            denom += w;
            acc.x = fmaf(w, bf2f(hv.x & 0xffffu), acc.x);
            acc.y = fmaf(w, bf2f(hv.x >> 16), acc.y);
            acc.z = fmaf(w, bf2f(hv.y & 0xffffu), acc.z);
            acc.w = fmaf(w, bf2f(hv.y >> 16), acc.w);
        }
    }
#pragma unroll
    for (int off = 16; off < 64; off <<= 1) {
        acc.x += __shfl_xor(acc.x, off, 64);
        acc.y += __shfl_xor(acc.y, off, 64);
        acc.z += __shfl_xor(acc.z, off, 64);
        acc.w += __shfl_xor(acc.w, off, 64);
        denom += __shfl_xor(denom, off, 64);
    }
    if (lane < 16) {
        float invd = 1.f / (denom + 1e-16f);
        float4 b = bias4[sub];
        float4 v;
        v.x = fmaf(acc.x, invd, b.x);
        v.y = fmaf(acc.y, invd, b.y);
        v.z = fmaf(acc.z, invd, b.z);
        v.w = fmaf(acc.w, invd, b.w);
        v.x = (v.x > 0.f) ? v.x : expm1f(v.x);
        v.y = (v.y > 0.f) ? v.y : expm1f(v.y);
        v.z = (v.z > 0.f) ? v.z : expm1f(v.z);
        v.w = (v.w > 0.f) ? v.w : expm1f(v.w);
        uint2 pv;
        pv.x = (unsigned)f2bf(v.x) | ((unsigned)f2bf(v.y) << 16);
        pv.y = (unsigned)f2bf(v.z) | ((unsigned)f2bf(v.w) << 16);
        *reinterpret_cast<uint2*>(&outb[(size_t)d * 64 + sub * 4]) = pv;
    }
}

__global__ __launch_bounds__(256) void k_gather2(const int* __restrict__ rowptr,
                                                 const int* __restrict__ col,
                                                 const uint2* __restrict__ Gb4,
                                                 const float* __restrict__ asrc,
                                                 const float* __restrict__ adst,
                                                 const float4* __restrict__ bias4,
                                                 int N, float4* __restrict__ out4) {
    int lane = threadIdx.x & 63;
    int d = (blockIdx.x << 2) + (threadIdx.x >> 6);
    if (d >= N) return;
    int g = lane >> 4;
    int sub = lane & 15;
    float adv = adst[d];
    int jb = rowptr[d], je = rowptr[d + 1];

    float4 acc = {0.f, 0.f, 0.f, 0.f};
    float denom = 0.f;
    for (int base = jb; base < je; base += 64) {
        int cnt = je - base; if (cnt > 64) cnt = 64;
        int myCol = (lane < cnt) ? col[base + lane] : 0;
#pragma unroll 2
        for (int u = 0; u < cnt; u += 4) {
            int eg = u + g;
            int s = __shfl(myCol, eg, 64);
            float e = asrc[s] + adv;
            e = (e > 0.f) ? e : LRELU * e;
            float w = (eg < cnt) ? __expf(e) : 0.f;
            uint2 hv = Gb4[(size_t)s * 16 + sub];
            denom += w;
            acc.x = fmaf(w, bf2f(hv.x & 0xffffu), acc.x);
            acc.y = fmaf(w, bf2f(hv.x >> 16), acc.y);
            acc.z = fmaf(w, bf2f(hv.y & 0xffffu), acc.z);
            acc.w = fmaf(w, bf2f(hv.y >> 16), acc.w);
        }
    }
#pragma unroll
    for (int off = 16; off < 64; off <<= 1) {
        acc.x += __shfl_xor(acc.x, off, 64);
        acc.y += __shfl_xor(acc.y, off, 64);
        acc.z += __shfl_xor(acc.z, off, 64);
        acc.w += __shfl_xor(acc.w, off, 64);
        denom += __shfl_xor(denom, off, 64);
    }
    float invd = 1.f / (denom + 1e-16f);
    float4 b = bias4[sub];
    float4 v;
    v.x = fmaf(acc.x, invd, b.x);
    v.y = fmaf(acc.y, invd, b.y);
    v.z = fmaf(acc.z, invd, b.z);
    v.w = fmaf(acc.w, invd, b.w);
    float m = fmaxf(fmaxf(v.x, v.y), fmaxf(v.z, v.w));
#pragma unroll
    for (int off = 1; off < 16; off <<= 1) m = fmaxf(m, __shfl_xor(m, off, 64));
    float se = __expf(v.x - m) + __expf(v.y - m) + __expf(v.z - m) + __expf(v.w - m);
#pragma unroll
    for (int off = 1; off < 16; off <<= 1) se += __shfl_xor(se, off, 64);
    float ls = m + __logf(se);
    if (lane < 16) {
        v.x -= ls; v.y -= ls; v.z -= ls; v.w -= ls;
        out4[(size_t)d * 16 + sub] = v;
    }
}

// ---------------- launch ----------------

extern "C" void kernel_launch(void* const* d_in, const int* in_sizes, int n_in,
                              void* d_out, int out_size, void* d_ws, size_t ws_size,
                              hipStream_t stream) {
    const float* x   = (const float*)d_in[0];
    const int*   ei  = (const int*)d_in[1];
    const float* W1  = (const float*)d_in[2];
    const float* as1 = (const float*)d_in[3];
    const float* ad1 = (const float*)d_in[4];
    const float* b1  = (const float*)d_in[5];
    const float* W2  = (const float*)d_in[6];
    const float* as2 = (const float*)d_in[7];
    const float* ad2 = (const float*)d_in[8];
    const float* b2  = (const float*)d_in[9];
    float* out = (float*)d_out;

    const int N = in_sizes[0] / 256;
    const int E = in_sizes[1] / 2;
    const int* src = ei;
    const int* dst = ei + E;
    const int NB = (N + BSZ - 1) >> BSH;
    const int nchunk = (E + CH - 1) / CH;

    char* ws = (char*)d_ws;
    size_t off = 0;
    auto alloc = [&](size_t bytes) -> void* {
        void* p = ws + off;
        off = (off + bytes + 255) & ~(size_t)255;
        return p;
    };
    int*      bcnt   = (int*)alloc((size_t)NB * 4);
    int*      boff   = (int*)alloc((size_t)(NB + 1) * 4);
    int*      bcur   = (int*)alloc((size_t)NB * 4);
    int*      rowptr = (int*)alloc((size_t)(N + 1) * 4);
    int*      col    = (int*)alloc((size_t)E * 4);
    unsigned* pairs  = (unsigned*)alloc((size_t)E * 4);
    unsigned short* wt1 = (unsigned short*)alloc(64 * 256 * 2);
    unsigned short* wt2 = (unsigned short*)alloc(64 * 64 * 2);
    unsigned short* h1b = (unsigned short*)alloc((size_t)N * 64 * 2);
    float* a_s1   = (float*)alloc((size_t)N * 8 * 4);
    float* a_d1   = (float*)alloc((size_t)N * 8 * 4);
    unsigned short* h2b = (unsigned short*)alloc((size_t)N * 64 * 2);
    unsigned short* gb  = (unsigned short*)alloc((size_t)N * 64 * 2);
    float* a_s2   = (float*)alloc((size_t)N * 4);
    float* a_d2   = (float*)alloc((size_t)N * 4);
    (void)ws_size; (void)n_in; (void)out_size;

    k_cvtW<<<80, 256, 0, stream>>>(W1, W2, wt1, wt2);

    hipMemsetAsync(bcnt, 0, (size_t)NB * 4, stream);
    k_bcount<<<nchunk, 256, 0, stream>>>(dst, E, NB, bcnt);
    k_bscan<<<1, 64, 0, stream>>>(bcnt, NB, boff, bcur);
    k_binscat1<<<nchunk, 256, 0, stream>>>(src, dst, E, NB, bcur, pairs);
    k_bucket<<<NB, 256, 0, stream>>>(boff, pairs, N, rowptr, col);

    int gblk = (N + 63) / 64;
    k_gemm1m<<<gblk, 256, 0, stream>>>(x, wt1, as1, ad1, N, h1b, a_s1, a_d1);

    int gather_blocks = (N + 3) / 4;
    k_gather1<<<gather_blocks, 256, 0, stream>>>(rowptr, col, (const uint2*)h1b,
                                                 a_s1, a_d1, (const float4*)b1, N, h2b);

    k_gemm2m<<<gblk, 256, 0, stream>>>(h2b, wt2, as2, ad2, N, gb, a_s2, a_d2);

    k_gather2<<<gather_blocks, 256, 0, stream>>>(rowptr, col, (const uint2*)gb,
                                                 a_s2, a_d2, (const float4*)b2, N,
                                                 (float4*)out);
}

// Round 7
// 290.212 us; speedup vs baseline: 2.9896x; 1.0638x over previous
//
#include <hip/hip_runtime.h>
#include <math.h>

#define LRELU 0.2f
#define BSH 7                  // 128 dsts per bucket
#define BSZ (1 << BSH)
#define CH 8192                // edges per phase-1 block

typedef __attribute__((ext_vector_type(8))) short bf16x8;
typedef __attribute__((ext_vector_type(4))) float f32x4;

static __device__ __forceinline__ float bf2f(unsigned int u16) {
    union { unsigned int i; float f; } c; c.i = u16 << 16; return c.f;
}
static __device__ __forceinline__ unsigned short f2bf(float f) {
    union { float f; unsigned int i; } c; c.f = f;
    unsigned int x = c.i;
    return (unsigned short)((x + 0x7fffu + ((x >> 16) & 1u)) >> 16);  // RNE
}

// ---------------- CSR build (bucket-centric) ----------

__global__ __launch_bounds__(256) void k_bcount(const int* __restrict__ dst, int E,
                                                int NB, int* __restrict__ bcnt) {
    __shared__ int cnt[512];
    int t = threadIdx.x;
    for (int b = t; b < 512; b += 256) cnt[b] = 0;
    __syncthreads();
    int e0 = blockIdx.x * CH;
    int e1 = e0 + CH; if (e1 > E) e1 = E;
    for (int i = e0 + t; i < e1; i += 256) atomicAdd(&cnt[dst[i] >> BSH], 1);
    __syncthreads();
    for (int b = t; b < NB; b += 256) {
        int c = cnt[b];
        if (c) atomicAdd(&bcnt[b], c);
    }
}

__global__ __launch_bounds__(64) void k_bscan(const int* __restrict__ bcnt, int NB,
                                              int* __restrict__ boff,
                                              int* __restrict__ bcur) {
    int lane = threadIdx.x;
    int run = 0;
    for (int base = 0; base < NB; base += 64) {
        int v = (base + lane < NB) ? bcnt[base + lane] : 0;
        int inc = v;
#pragma unroll
        for (int off = 1; off < 64; off <<= 1) {
            int t = __shfl_up(inc, off, 64);
            if (lane >= off) inc += t;
        }
        if (base + lane < NB) {
            int e = run + inc - v;
            boff[base + lane] = e;
            bcur[base + lane] = e;
        }
        run += __shfl(inc, 63, 64);
    }
    if (lane == 0) boff[NB] = run;
}

__global__ __launch_bounds__(256) void k_binscat1(const int* __restrict__ src,
                                                  const int* __restrict__ dst,
                                                  int E, int NB,
                                                  int* __restrict__ bcur,
                                                  unsigned* __restrict__ pairs) {
    __shared__ int cnt[512];
    __shared__ int lds_d[CH];
    int t = threadIdx.x;
    int e0 = blockIdx.x * CH;
    int e1 = e0 + CH; if (e1 > E) e1 = E;
    int n = e1 - e0;
    for (int b = t; b < 512; b += 256) cnt[b] = 0;
    __syncthreads();
    for (int i = t; i < n; i += 256) {
        int d = dst[e0 + i];
        lds_d[i] = d;
        atomicAdd(&cnt[d >> BSH], 1);
    }
    __syncthreads();
    for (int b = t; b < NB; b += 256) {
        int c = cnt[b];
        cnt[b] = c ? atomicAdd(&bcur[b], c) : 0;
    }
    __syncthreads();
    for (int i = t; i < n; i += 256) {
        int d = lds_d[i];
        int p = atomicAdd(&cnt[d >> BSH], 1);
        pairs[p] = ((unsigned)src[e0 + i] << BSH) | (unsigned)(d & (BSZ - 1));
    }
}

__global__ __launch_bounds__(256) void k_bucket(const int* __restrict__ boff,
                                                const unsigned* __restrict__ pairs,
                                                int N, int* __restrict__ rowptr,
                                                int* __restrict__ col) {
    __shared__ int cnt[BSZ];
    __shared__ int cur[BSZ];
    int t = threadIdx.x;
    int b = blockIdx.x;
    int dlo = b << BSH;
    int dhi = dlo + BSZ; if (dhi > N) dhi = N;
    int nd = dhi - dlo;
    int jb = boff[b], je = boff[b + 1];
    if (t < BSZ) cnt[t] = 0;
    __syncthreads();
    for (int j = jb + t; j < je; j += 256) atomicAdd(&cnt[pairs[j] & (BSZ - 1)], 1);
    __syncthreads();
    if (t < 64) {
        int v0 = cnt[t], v1 = cnt[64 + t];
        int i0 = v0;
#pragma unroll
        for (int off = 1; off < 64; off <<= 1) {
            int q = __shfl_up(i0, off, 64);
            if (t >= off) i0 += q;
        }
        int tot0 = __shfl(i0, 63, 64);
        int i1 = v1;
#pragma unroll
        for (int off = 1; off < 64; off <<= 1) {
            int q = __shfl_up(i1, off, 64);
            if (t >= off) i1 += q;
        }
        int e0x = jb + i0 - v0;
        int e1x = jb + tot0 + i1 - v1;
        cur[t] = e0x;
        cur[64 + t] = e1x;
        if (t < nd) rowptr[dlo + t] = e0x;
        if (64 + t < nd) rowptr[dlo + 64 + t] = e1x;
        if (t == 0 && dhi == N) rowptr[N] = je;
    }
    __syncthreads();
    for (int j = jb + t; j < je; j += 256) {
        unsigned pk = pairs[j];
        int p = atomicAdd(&cur[pk & (BSZ - 1)], 1);
        col[p] = (int)(pk >> BSH);
    }
}

// ---------------- weight convert/transpose to bf16 ----------------
__global__ __launch_bounds__(256) void k_cvtW(const float* __restrict__ W1,
                                              const float* __restrict__ W2,
                                              unsigned short* __restrict__ Wt1,
                                              unsigned short* __restrict__ Wt2) {
    int idx = blockIdx.x * 256 + threadIdx.x;
    if (idx < 16384) {
        int n = idx >> 8, k = idx & 255;
        Wt1[idx] = f2bf(W1[k * 64 + n]);
    } else if (idx < 16384 + 4096) {
        int j = idx - 16384;
        int n = j >> 6, k = j & 63;
        Wt2[j] = f2bf(W2[k * 64 + n]);
    }
}

// ---------------- MFMA GEMM1 ----------------
__global__ __launch_bounds__(256) void k_gemm1m(const float* __restrict__ X,
                                                const unsigned short* __restrict__ Wt,
                                                const float* __restrict__ atts,
                                                const float* __restrict__ attd,
                                                int N, unsigned short* __restrict__ Hb,
                                                float* __restrict__ asrc,
                                                float* __restrict__ adst) {
    __shared__ short Xl[64 * 256];
    int t = threadIdx.x, l = t & 63, w = t >> 6;
    int rblk = blockIdx.x * 64;

    int half = l >> 5;
    int c8 = (l & 31) * 8;
#pragma unroll
    for (int i = 0; i < 8; ++i) {
        int rl = w * 16 + i * 2 + half;
        int row = rblk + rl;
        float4 x0 = {0.f, 0.f, 0.f, 0.f}, x1 = {0.f, 0.f, 0.f, 0.f};
        if (row < N) {
            x0 = *reinterpret_cast<const float4*>(X + (size_t)row * 256 + c8);
            x1 = *reinterpret_cast<const float4*>(X + (size_t)row * 256 + c8 + 4);
        }
        bf16x8 p;
        p[0] = (short)f2bf(x0.x); p[1] = (short)f2bf(x0.y);
        p[2] = (short)f2bf(x0.z); p[3] = (short)f2bf(x0.w);
        p[4] = (short)f2bf(x1.x); p[5] = (short)f2bf(x1.y);
        p[6] = (short)f2bf(x1.z); p[7] = (short)f2bf(x1.w);
        int g = (l & 31) ^ (rl & 7);
        *reinterpret_cast<bf16x8*>(&Xl[rl * 256 + g * 8]) = p;
    }

    int m = l & 15, quad = l >> 4;
    int rl = w * 16 + m;
    f32x4 acc0 = {0.f, 0.f, 0.f, 0.f}, acc1 = acc0, acc2 = acc0, acc3 = acc0;
#pragma unroll
    for (int tt = 0; tt < 8; ++tt) {
        int g = (tt * 4 + quad) ^ (m & 7);
        bf16x8 a = *reinterpret_cast<const bf16x8*>(&Xl[rl * 256 + g * 8]);
        int kk = tt * 32 + quad * 8;
        bf16x8 b0 = *reinterpret_cast<const bf16x8*>(&Wt[(0 * 16 + m) * 256 + kk]);
        bf16x8 b1 = *reinterpret_cast<const bf16x8*>(&Wt[(1 * 16 + m) * 256 + kk]);
        bf16x8 b2 = *reinterpret_cast<const bf16x8*>(&Wt[(2 * 16 + m) * 256 + kk]);
        bf16x8 b3 = *reinterpret_cast<const bf16x8*>(&Wt[(3 * 16 + m) * 256 + kk]);
        acc0 = __builtin_amdgcn_mfma_f32_16x16x32_bf16(a, b0, acc0, 0, 0, 0);
        acc1 = __builtin_amdgcn_mfma_f32_16x16x32_bf16(a, b1, acc1, 0, 0, 0);
        acc2 = __builtin_amdgcn_mfma_f32_16x16x32_bf16(a, b2, acc2, 0, 0, 0);
        acc3 = __builtin_amdgcn_mfma_f32_16x16x32_bf16(a, b3, acc3, 0, 0, 0);
    }

    int r0 = rblk + w * 16;
    f32x4 accs[4] = {acc0, acc1, acc2, acc3};
#pragma unroll
    for (int nt = 0; nt < 4; ++nt) {
        int cn = nt * 16 + m;
        float av_s = atts[cn], av_d = attd[cn];
#pragma unroll
        for (int r = 0; r < 4; ++r) {
            int row = r0 + quad * 4 + r;
            float hv = accs[nt][r];
            if (row < N) Hb[(size_t)row * 64 + cn] = f2bf(hv);
            float vs = hv * av_s, vd = hv * av_d;
            vs += __shfl_xor(vs, 1, 64); vs += __shfl_xor(vs, 2, 64); vs += __shfl_xor(vs, 4, 64);
            vd += __shfl_xor(vd, 1, 64); vd += __shfl_xor(vd, 2, 64); vd += __shfl_xor(vd, 4, 64);
            if ((m & 7) == 0 && row < N) {
                int head = cn >> 3;
                asrc[row * 8 + head] = vs;
                adst[row * 8 + head] = vd;
            }
        }
    }
}

// ---------------- MFMA GEMM2 ----------------
__global__ __launch_bounds__(256) void k_gemm2m(const unsigned short* __restrict__ Xb,
                                                const unsigned short* __restrict__ Wt,
                                                const float* __restrict__ atts,
                                                const float* __restrict__ attd,
                                                int N, unsigned short* __restrict__ Gb,
                                                float* __restrict__ asrc,
                                                float* __restrict__ adst) {
    int t = threadIdx.x, l = t & 63, w = t >> 6;
    int rblk = blockIdx.x * 64;
    int m = l & 15, quad = l >> 4;
    int row = rblk + w * 16 + m;
    int rowc = (row < N) ? row : 0;

    f32x4 acc0 = {0.f, 0.f, 0.f, 0.f}, acc1 = acc0, acc2 = acc0, acc3 = acc0;
#pragma unroll
    for (int tt = 0; tt < 2; ++tt) {
        int kk = tt * 32 + quad * 8;
        bf16x8 a = *reinterpret_cast<const bf16x8*>(&Xb[(size_t)rowc * 64 + kk]);
        bf16x8 b0 = *reinterpret_cast<const bf16x8*>(&Wt[(0 * 16 + m) * 64 + kk]);
        bf16x8 b1 = *reinterpret_cast<const bf16x8*>(&Wt[(1 * 16 + m) * 64 + kk]);
        bf16x8 b2 = *reinterpret_cast<const bf16x8*>(&Wt[(2 * 16 + m) * 64 + kk]);
        bf16x8 b3 = *reinterpret_cast<const bf16x8*>(&Wt[(3 * 16 + m) * 64 + kk]);
        acc0 = __builtin_amdgcn_mfma_f32_16x16x32_bf16(a, b0, acc0, 0, 0, 0);
        acc1 = __builtin_amdgcn_mfma_f32_16x16x32_bf16(a, b1, acc1, 0, 0, 0);
        acc2 = __builtin_amdgcn_mfma_f32_16x16x32_bf16(a, b2, acc2, 0, 0, 0);
        acc3 = __builtin_amdgcn_mfma_f32_16x16x32_bf16(a, b3, acc3, 0, 0, 0);
    }

    int r0 = rblk + w * 16;
    f32x4 accs[4] = {acc0, acc1, acc2, acc3};
#pragma unroll
    for (int r = 0; r < 4; ++r) {
        int orow = r0 + quad * 4 + r;
        float vs = 0.f, vd = 0.f;
#pragma unroll
        for (int nt = 0; nt < 4; ++nt) {
            int cn = nt * 16 + m;
            float hv = accs[nt][r];
            if (orow < N) Gb[(size_t)orow * 64 + cn] = f2bf(hv);
            vs = fmaf(hv, atts[cn], vs);
            vd = fmaf(hv, attd[cn], vd);
        }
#pragma unroll
        for (int off = 1; off < 16; off <<= 1) {
            vs += __shfl_xor(vs, off, 64);
            vd += __shfl_xor(vd, off, 64);
        }
        if (m == 0 && orow < N) { asrc[orow] = vs; adst[orow] = vd; }
    }
}

// ------- Fused per-dst gather: 8 edges in flight x 8 channels/lane -------
// lane = g*8 + sub.  g = edge slot, sub = head / channel-octet.

__global__ __launch_bounds__(256) void k_gather1(const int* __restrict__ rowptr,
                                                 const int* __restrict__ col,
                                                 const uint4* __restrict__ Hb8,
                                                 const float* __restrict__ asrc,
                                                 const float* __restrict__ adst,
                                                 const float* __restrict__ bias,
                                                 int N, unsigned short* __restrict__ outb) {
    int lane = threadIdx.x & 63;
    int d = (blockIdx.x << 2) + (threadIdx.x >> 6);
    if (d >= N) return;
    int g = lane >> 3;        // edge slot (8 in flight)
    int sub = lane & 7;       // head == channel octet
    float adv = adst[d * 8 + sub];
    int jb = rowptr[d], je = rowptr[d + 1];

    float acc[8] = {0.f, 0.f, 0.f, 0.f, 0.f, 0.f, 0.f, 0.f};
    float denom = 0.f;
    for (int base = jb; base < je; base += 64) {
        int cnt = je - base; if (cnt > 64) cnt = 64;
        int myCol = (lane < cnt) ? col[base + lane] : 0;
#pragma unroll 2
        for (int u = 0; u < cnt; u += 8) {
            int eg = u + g;
            int s = __shfl(myCol, eg, 64);
            float e = asrc[s * 8 + sub] + adv;
            e = (e > 0.f) ? e : LRELU * e;
            float w = (eg < cnt) ? __expf(e) : 0.f;
            uint4 hv = Hb8[(size_t)s * 8 + sub];
            denom += w;
            acc[0] = fmaf(w, bf2f(hv.x & 0xffffu), acc[0]);
            acc[1] = fmaf(w, bf2f(hv.x >> 16), acc[1]);
            acc[2] = fmaf(w, bf2f(hv.y & 0xffffu), acc[2]);
            acc[3] = fmaf(w, bf2f(hv.y >> 16), acc[3]);
            acc[4] = fmaf(w, bf2f(hv.z & 0xffffu), acc[4]);
            acc[5] = fmaf(w, bf2f(hv.z >> 16), acc[5]);
            acc[6] = fmaf(w, bf2f(hv.w & 0xffffu), acc[6]);
            acc[7] = fmaf(w, bf2f(hv.w >> 16), acc[7]);
        }
    }
#pragma unroll
    for (int off = 8; off < 64; off <<= 1) {
#pragma unroll
        for (int c = 0; c < 8; ++c) acc[c] += __shfl_xor(acc[c], off, 64);
        denom += __shfl_xor(denom, off, 64);
    }
    if (lane < 8) {
        float invd = 1.f / (denom + 1e-16f);
        unsigned short pk[8];
#pragma unroll
        for (int c = 0; c < 8; ++c) {
            float v = fmaf(acc[c], invd, bias[sub * 8 + c]);
            v = (v > 0.f) ? v : expm1f(v);
            pk[c] = f2bf(v);
        }
        uint4 pv;
        pv.x = (unsigned)pk[0] | ((unsigned)pk[1] << 16);
        pv.y = (unsigned)pk[2] | ((unsigned)pk[3] << 16);
        pv.z = (unsigned)pk[4] | ((unsigned)pk[5] << 16);
        pv.w = (unsigned)pk[6] | ((unsigned)pk[7] << 16);
        *reinterpret_cast<uint4*>(&outb[(size_t)d * 64 + sub * 8]) = pv;
    }
}

__global__ __launch_bounds__(256) void k_gather2(const int* __restrict__ rowptr,
                                                 const int* __restrict__ col,
                                                 const uint4* __restrict__ Gb8,
                                                 const float* __restrict__ asrc,
                                                 const float* __restrict__ adst,
                                                 const float* __restrict__ bias,
                                                 int N, float* __restrict__ out) {
    int lane = threadIdx.x & 63;
    int d = (blockIdx.x << 2) + (threadIdx.x >> 6);
    if (d >= N) return;
    int g = lane >> 3;
    int sub = lane & 7;
    float adv = adst[d];
    int jb = rowptr[d], je = rowptr[d + 1];

    float acc[8] = {0.f, 0.f, 0.f, 0.f, 0.f, 0.f, 0.f, 0.f};
    float denom = 0.f;
    for (int base = jb; base < je; base += 64) {
        int cnt = je - base; if (cnt > 64) cnt = 64;
        int myCol = (lane < cnt) ? col[base + lane] : 0;
#pragma unroll 2
        for (int u = 0; u < cnt; u += 8) {
            int eg = u + g;
            int s = __shfl(myCol, eg, 64);
            float e = asrc[s] + adv;
            e = (e > 0.f) ? e : LRELU * e;
            float w = (eg < cnt) ? __expf(e) : 0.f;
            uint4 hv = Gb8[(size_t)s * 8 + sub];
            denom += w;
            acc[0] = fmaf(w, bf2f(hv.x & 0xffffu), acc[0]);
            acc[1] = fmaf(w, bf2f(hv.x >> 16), acc[1]);
            acc[2] = fmaf(w, bf2f(hv.y & 0xffffu), acc[2]);
            acc[3] = fmaf(w, bf2f(hv.y >> 16), acc[3]);
            acc[4] = fmaf(w, bf2f(hv.z & 0xffffu), acc[4]);
            acc[5] = fmaf(w, bf2f(hv.z >> 16), acc[5]);
            acc[6] = fmaf(w, bf2f(hv.w & 0xffffu), acc[6]);
            acc[7] = fmaf(w, bf2f(hv.w >> 16), acc[7]);
        }
    }
#pragma unroll
    for (int off = 8; off < 64; off <<= 1) {
#pragma unroll
        for (int c = 0; c < 8; ++c) acc[c] += __shfl_xor(acc[c], off, 64);
        denom += __shfl_xor(denom, off, 64);
    }
    float invd = 1.f / (denom + 1e-16f);
    float v[8];
#pragma unroll
    for (int c = 0; c < 8; ++c) v[c] = fmaf(acc[c], invd, bias[sub * 8 + c]);
    // log_softmax over 64 channels: lanes 0..7 each hold an octet (xor group closed)
    float m = v[0];
#pragma unroll
    for (int c = 1; c < 8; ++c) m = fmaxf(m, v[c]);
#pragma unroll
    for (int off = 1; off < 8; off <<= 1) m = fmaxf(m, __shfl_xor(m, off, 64));
    float se = 0.f;
#pragma unroll
    for (int c = 0; c < 8; ++c) se += __expf(v[c] - m);
#pragma unroll
    for (int off = 1; off < 8; off <<= 1) se += __shfl_xor(se, off, 64);
    float ls = m + __logf(se);
    if (lane < 8) {
        float4 o0, o1;
        o0.x = v[0] - ls; o0.y = v[1] - ls; o0.z = v[2] - ls; o0.w = v[3] - ls;
        o1.x = v[4] - ls; o1.y = v[5] - ls; o1.z = v[6] - ls; o1.w = v[7] - ls;
        *reinterpret_cast<float4*>(&out[(size_t)d * 64 + sub * 8]) = o0;
        *reinterpret_cast<float4*>(&out[(size_t)d * 64 + sub * 8 + 4]) = o1;
    }
}

// ---------------- launch ----------------

extern "C" void kernel_launch(void* const* d_in, const int* in_sizes, int n_in,
                              void* d_out, int out_size, void* d_ws, size_t ws_size,
                              hipStream_t stream) {
    const float* x   = (const float*)d_in[0];
    const int*   ei  = (const int*)d_in[1];
    const float* W1  = (const float*)d_in[2];
    const float* as1 = (const float*)d_in[3];
    const float* ad1 = (const float*)d_in[4];
    const float* b1  = (const float*)d_in[5];
    const float* W2  = (const float*)d_in[6];
    const float* as2 = (const float*)d_in[7];
    const float* ad2 = (const float*)d_in[8];
    const float* b2  = (const float*)d_in[9];
    float* out = (float*)d_out;

    const int N = in_sizes[0] / 256;
    const int E = in_sizes[1] / 2;
    const int* src = ei;
    const int* dst = ei + E;
    const int NB = (N + BSZ - 1) >> BSH;
    const int nchunk = (E + CH - 1) / CH;

    char* ws = (char*)d_ws;
    size_t off = 0;
    auto alloc = [&](size_t bytes) -> void* {
        void* p = ws + off;
        off = (off + bytes + 255) & ~(size_t)255;
        return p;
    };
    int*      bcnt   = (int*)alloc((size_t)NB * 4);
    int*      boff   = (int*)alloc((size_t)(NB + 1) * 4);
    int*      bcur   = (int*)alloc((size_t)NB * 4);
    int*      rowptr = (int*)alloc((size_t)(N + 1) * 4);
    int*      col    = (int*)alloc((size_t)E * 4);
    unsigned* pairs  = (unsigned*)alloc((size_t)E * 4);
    unsigned short* wt1 = (unsigned short*)alloc(64 * 256 * 2);
    unsigned short* wt2 = (unsigned short*)alloc(64 * 64 * 2);
    unsigned short* h1b = (unsigned short*)alloc((size_t)N * 64 * 2);
    float* a_s1   = (float*)alloc((size_t)N * 8 * 4);
    float* a_d1   = (float*)alloc((size_t)N * 8 * 4);
    unsigned short* h2b = (unsigned short*)alloc((size_t)N * 64 * 2);
    unsigned short* gb  = (unsigned short*)alloc((size_t)N * 64 * 2);
    float* a_s2   = (float*)alloc((size_t)N * 4);
    float* a_d2   = (float*)alloc((size_t)N * 4);
    (void)ws_size; (void)n_in; (void)out_size;

    k_cvtW<<<80, 256, 0, stream>>>(W1, W2, wt1, wt2);

    hipMemsetAsync(bcnt, 0, (size_t)NB * 4, stream);
    k_bcount<<<nchunk, 256, 0, stream>>>(dst, E, NB, bcnt);
    k_bscan<<<1, 64, 0, stream>>>(bcnt, NB, boff, bcur);
    k_binscat1<<<nchunk, 256, 0, stream>>>(src, dst, E, NB, bcur, pairs);
    k_bucket<<<NB, 256, 0, stream>>>(boff, pairs, N, rowptr, col);

    int gblk = (N + 63) / 64;
    k_gemm1m<<<gblk, 256, 0, stream>>>(x, wt1, as1, ad1, N, h1b, a_s1, a_d1);

    int gather_blocks = (N + 3) / 4;
    k_gather1<<<gather_blocks, 256, 0, stream>>>(rowptr, col, (const uint4*)h1b,
                                                 a_s1, a_d1, b1, N, h2b);

    k_gemm2m<<<gblk, 256, 0, stream>>>(h2b, wt2, as2, ad2, N, gb, a_s2, a_d2);

    k_gather2<<<gather_blocks, 256, 0, stream>>>(rowptr, col, (const uint4*)gb,
                                                 a_s2, a_d2, b2, N, out);
}

// Round 8
// 288.927 us; speedup vs baseline: 3.0029x; 1.0044x over previous
//
#include <hip/hip_runtime.h>
#include <math.h>

#define LRELU 0.2f
#define BSH 7                  // 128 dsts per bucket
#define BSZ (1 << BSH)
#define CH 8192                // edges per phase-1 block

typedef __attribute__((ext_vector_type(8))) short bf16x8;
typedef __attribute__((ext_vector_type(4))) float f32x4;

static __device__ __forceinline__ float bf2f(unsigned int u16) {
    union { unsigned int i; float f; } c; c.i = u16 << 16; return c.f;
}
static __device__ __forceinline__ unsigned short f2bf(float f) {
    union { float f; unsigned int i; } c; c.f = f;
    unsigned int x = c.i;
    return (unsigned short)((x + 0x7fffu + ((x >> 16) & 1u)) >> 16);  // RNE
}

// ---------------- CSR build (bucket-centric) ----------

__global__ __launch_bounds__(256) void k_bcount(const int* __restrict__ dst, int E,
                                                int NB, int* __restrict__ bcnt) {
    __shared__ int cnt[512];
    int t = threadIdx.x;
    for (int b = t; b < 512; b += 256) cnt[b] = 0;
    __syncthreads();
    int e0 = blockIdx.x * CH;
    int e1 = e0 + CH; if (e1 > E) e1 = E;
    for (int i = e0 + t; i < e1; i += 256) atomicAdd(&cnt[dst[i] >> BSH], 1);
    __syncthreads();
    for (int b = t; b < NB; b += 256) {
        int c = cnt[b];
        if (c) atomicAdd(&bcnt[b], c);
    }
}

__global__ __launch_bounds__(64) void k_bscan(const int* __restrict__ bcnt, int NB,
                                              int* __restrict__ boff,
                                              int* __restrict__ bcur) {
    int lane = threadIdx.x;
    int run = 0;
    for (int base = 0; base < NB; base += 64) {
        int v = (base + lane < NB) ? bcnt[base + lane] : 0;
        int inc = v;
#pragma unroll
        for (int off = 1; off < 64; off <<= 1) {
            int t = __shfl_up(inc, off, 64);
            if (lane >= off) inc += t;
        }
        if (base + lane < NB) {
            int e = run + inc - v;
            boff[base + lane] = e;
            bcur[base + lane] = e;
        }
        run += __shfl(inc, 63, 64);
    }
    if (lane == 0) boff[NB] = run;
}

__global__ __launch_bounds__(256) void k_binscat1(const int* __restrict__ src,
                                                  const int* __restrict__ dst,
                                                  int E, int NB,
                                                  int* __restrict__ bcur,
                                                  unsigned* __restrict__ pairs) {
    __shared__ int cnt[512];
    __shared__ int lds_d[CH];
    int t = threadIdx.x;
    int e0 = blockIdx.x * CH;
    int e1 = e0 + CH; if (e1 > E) e1 = E;
    int n = e1 - e0;
    for (int b = t; b < 512; b += 256) cnt[b] = 0;
    __syncthreads();
    for (int i = t; i < n; i += 256) {
        int d = dst[e0 + i];
        lds_d[i] = d;
        atomicAdd(&cnt[d >> BSH], 1);
    }
    __syncthreads();
    for (int b = t; b < NB; b += 256) {
        int c = cnt[b];
        cnt[b] = c ? atomicAdd(&bcur[b], c) : 0;
    }
    __syncthreads();
    for (int i = t; i < n; i += 256) {
        int d = lds_d[i];
        int p = atomicAdd(&cnt[d >> BSH], 1);
        pairs[p] = ((unsigned)src[e0 + i] << BSH) | (unsigned)(d & (BSZ - 1));
    }
}

__global__ __launch_bounds__(256) void k_bucket(const int* __restrict__ boff,
                                                const unsigned* __restrict__ pairs,
                                                int N, int* __restrict__ rowptr,
                                                int* __restrict__ col) {
    __shared__ int cnt[BSZ];
    __shared__ int cur[BSZ];
    int t = threadIdx.x;
    int b = blockIdx.x;
    int dlo = b << BSH;
    int dhi = dlo + BSZ; if (dhi > N) dhi = N;
    int nd = dhi - dlo;
    int jb = boff[b], je = boff[b + 1];
    if (t < BSZ) cnt[t] = 0;
    __syncthreads();
    for (int j = jb + t; j < je; j += 256) atomicAdd(&cnt[pairs[j] & (BSZ - 1)], 1);
    __syncthreads();
    if (t < 64) {
        int v0 = cnt[t], v1 = cnt[64 + t];
        int i0 = v0;
#pragma unroll
        for (int off = 1; off < 64; off <<= 1) {
            int q = __shfl_up(i0, off, 64);
            if (t >= off) i0 += q;
        }
        int tot0 = __shfl(i0, 63, 64);
        int i1 = v1;
#pragma unroll
        for (int off = 1; off < 64; off <<= 1) {
            int q = __shfl_up(i1, off, 64);
            if (t >= off) i1 += q;
        }
        int e0x = jb + i0 - v0;
        int e1x = jb + tot0 + i1 - v1;
        cur[t] = e0x;
        cur[64 + t] = e1x;
        if (t < nd) rowptr[dlo + t] = e0x;
        if (64 + t < nd) rowptr[dlo + 64 + t] = e1x;
        if (t == 0 && dhi == N) rowptr[N] = je;
    }
    __syncthreads();
    for (int j = jb + t; j < je; j += 256) {
        unsigned pk = pairs[j];
        int p = atomicAdd(&cur[pk & (BSZ - 1)], 1);
        col[p] = (int)(pk >> BSH);
    }
}

// ---------------- weight convert/transpose to bf16 ----------------
__global__ __launch_bounds__(256) void k_cvtW(const float* __restrict__ W1,
                                              const float* __restrict__ W2,
                                              unsigned short* __restrict__ Wt1,
                                              unsigned short* __restrict__ Wt2) {
    int idx = blockIdx.x * 256 + threadIdx.x;
    if (idx < 16384) {
        int n = idx >> 8, k = idx & 255;
        Wt1[idx] = f2bf(W1[k * 64 + n]);
    } else if (idx < 16384 + 4096) {
        int j = idx - 16384;
        int n = j >> 6, k = j & 63;
        Wt2[j] = f2bf(W2[k * 64 + n]);
    }
}

// ---------------- MFMA GEMM1 ----------------
__global__ __launch_bounds__(256) void k_gemm1m(const float* __restrict__ X,
                                                const unsigned short* __restrict__ Wt,
                                                const float* __restrict__ atts,
                                                const float* __restrict__ attd,
                                                int N, unsigned short* __restrict__ Hb,
                                                float* __restrict__ asrc,
                                                float* __restrict__ adst) {
    __shared__ short Xl[64 * 256];
    int t = threadIdx.x, l = t & 63, w = t >> 6;
    int rblk = blockIdx.x * 64;

    int half = l >> 5;
    int c8 = (l & 31) * 8;
#pragma unroll
    for (int i = 0; i < 8; ++i) {
        int rl = w * 16 + i * 2 + half;
        int row = rblk + rl;
        float4 x0 = {0.f, 0.f, 0.f, 0.f}, x1 = {0.f, 0.f, 0.f, 0.f};
        if (row < N) {
            x0 = *reinterpret_cast<const float4*>(X + (size_t)row * 256 + c8);
            x1 = *reinterpret_cast<const float4*>(X + (size_t)row * 256 + c8 + 4);
        }
        bf16x8 p;
        p[0] = (short)f2bf(x0.x); p[1] = (short)f2bf(x0.y);
        p[2] = (short)f2bf(x0.z); p[3] = (short)f2bf(x0.w);
        p[4] = (short)f2bf(x1.x); p[5] = (short)f2bf(x1.y);
        p[6] = (short)f2bf(x1.z); p[7] = (short)f2bf(x1.w);
        int g = (l & 31) ^ (rl & 7);
        *reinterpret_cast<bf16x8*>(&Xl[rl * 256 + g * 8]) = p;
    }

    int m = l & 15, quad = l >> 4;
    int rl = w * 16 + m;
    f32x4 acc0 = {0.f, 0.f, 0.f, 0.f}, acc1 = acc0, acc2 = acc0, acc3 = acc0;
#pragma unroll
    for (int tt = 0; tt < 8; ++tt) {
        int g = (tt * 4 + quad) ^ (m & 7);
        bf16x8 a = *reinterpret_cast<const bf16x8*>(&Xl[rl * 256 + g * 8]);
        int kk = tt * 32 + quad * 8;
        bf16x8 b0 = *reinterpret_cast<const bf16x8*>(&Wt[(0 * 16 + m) * 256 + kk]);
        bf16x8 b1 = *reinterpret_cast<const bf16x8*>(&Wt[(1 * 16 + m) * 256 + kk]);
        bf16x8 b2 = *reinterpret_cast<const bf16x8*>(&Wt[(2 * 16 + m) * 256 + kk]);
        bf16x8 b3 = *reinterpret_cast<const bf16x8*>(&Wt[(3 * 16 + m) * 256 + kk]);
        acc0 = __builtin_amdgcn_mfma_f32_16x16x32_bf16(a, b0, acc0, 0, 0, 0);
        acc1 = __builtin_amdgcn_mfma_f32_16x16x32_bf16(a, b1, acc1, 0, 0, 0);
        acc2 = __builtin_amdgcn_mfma_f32_16x16x32_bf16(a, b2, acc2, 0, 0, 0);
        acc3 = __builtin_amdgcn_mfma_f32_16x16x32_bf16(a, b3, acc3, 0, 0, 0);
    }

    int r0 = rblk + w * 16;
    f32x4 accs[4] = {acc0, acc1, acc2, acc3};
#pragma unroll
    for (int nt = 0; nt < 4; ++nt) {
        int cn = nt * 16 + m;
        float av_s = atts[cn], av_d = attd[cn];
#pragma unroll
        for (int r = 0; r < 4; ++r) {
            int row = r0 + quad * 4 + r;
            float hv = accs[nt][r];
            if (row < N) Hb[(size_t)row * 64 + cn] = f2bf(hv);
            float vs = hv * av_s, vd = hv * av_d;
            vs += __shfl_xor(vs, 1, 64); vs += __shfl_xor(vs, 2, 64); vs += __shfl_xor(vs, 4, 64);
            vd += __shfl_xor(vd, 1, 64); vd += __shfl_xor(vd, 2, 64); vd += __shfl_xor(vd, 4, 64);
            if ((m & 7) == 0 && row < N) {
                int head = cn >> 3;
                asrc[row * 8 + head] = vs;
                adst[row * 8 + head] = vd;
            }
        }
    }
}

// ---------------- MFMA GEMM2 ----------------
__global__ __launch_bounds__(256) void k_gemm2m(const unsigned short* __restrict__ Xb,
                                                const unsigned short* __restrict__ Wt,
                                                const float* __restrict__ atts,
                                                const float* __restrict__ attd,
                                                int N, unsigned short* __restrict__ Gb,
                                                float* __restrict__ asrc,
                                                float* __restrict__ adst) {
    int t = threadIdx.x, l = t & 63, w = t >> 6;
    int rblk = blockIdx.x * 64;
    int m = l & 15, quad = l >> 4;
    int row = rblk + w * 16 + m;
    int rowc = (row < N) ? row : 0;

    f32x4 acc0 = {0.f, 0.f, 0.f, 0.f}, acc1 = acc0, acc2 = acc0, acc3 = acc0;
#pragma unroll
    for (int tt = 0; tt < 2; ++tt) {
        int kk = tt * 32 + quad * 8;
        bf16x8 a = *reinterpret_cast<const bf16x8*>(&Xb[(size_t)rowc * 64 + kk]);
        bf16x8 b0 = *reinterpret_cast<const bf16x8*>(&Wt[(0 * 16 + m) * 64 + kk]);
        bf16x8 b1 = *reinterpret_cast<const bf16x8*>(&Wt[(1 * 16 + m) * 64 + kk]);
        bf16x8 b2 = *reinterpret_cast<const bf16x8*>(&Wt[(2 * 16 + m) * 64 + kk]);
        bf16x8 b3 = *reinterpret_cast<const bf16x8*>(&Wt[(3 * 16 + m) * 64 + kk]);
        acc0 = __builtin_amdgcn_mfma_f32_16x16x32_bf16(a, b0, acc0, 0, 0, 0);
        acc1 = __builtin_amdgcn_mfma_f32_16x16x32_bf16(a, b1, acc1, 0, 0, 0);
        acc2 = __builtin_amdgcn_mfma_f32_16x16x32_bf16(a, b2, acc2, 0, 0, 0);
        acc3 = __builtin_amdgcn_mfma_f32_16x16x32_bf16(a, b3, acc3, 0, 0, 0);
    }

    int r0 = rblk + w * 16;
    f32x4 accs[4] = {acc0, acc1, acc2, acc3};
#pragma unroll
    for (int r = 0; r < 4; ++r) {
        int orow = r0 + quad * 4 + r;
        float vs = 0.f, vd = 0.f;
#pragma unroll
        for (int nt = 0; nt < 4; ++nt) {
            int cn = nt * 16 + m;
            float hv = accs[nt][r];
            if (orow < N) Gb[(size_t)orow * 64 + cn] = f2bf(hv);
            vs = fmaf(hv, atts[cn], vs);
            vd = fmaf(hv, attd[cn], vd);
        }
#pragma unroll
        for (int off = 1; off < 16; off <<= 1) {
            vs += __shfl_xor(vs, off, 64);
            vd += __shfl_xor(vd, off, 64);
        }
        if (m == 0 && orow < N) { asrc[orow] = vs; adst[orow] = vd; }
    }
}

// ------- Fused per-dst gather: 8 edges x 8 channels/lane, no shuffles -------
// lane = g*8 + sub.  Edge id read directly: col[base+u+g] (broadcast in group).

__global__ __launch_bounds__(256) void k_gather1(const int* __restrict__ rowptr,
                                                 const int* __restrict__ col,
                                                 const uint4* __restrict__ Hb8,
                                                 const float* __restrict__ asrc,
                                                 const float* __restrict__ adst,
                                                 const float* __restrict__ bias,
                                                 int N, int Emax,
                                                 unsigned short* __restrict__ outb) {
    int lane = threadIdx.x & 63;
    int d = (blockIdx.x << 2) + (threadIdx.x >> 6);
    if (d >= N) return;
    int g = lane >> 3;        // edge slot (8 in flight)
    int sub = lane & 7;       // head == channel octet
    float adv = adst[d * 8 + sub];
    int jb = rowptr[d], je = rowptr[d + 1];

    float acc[8] = {0.f, 0.f, 0.f, 0.f, 0.f, 0.f, 0.f, 0.f};
    float denom = 0.f;
#pragma unroll 4
    for (int u = jb + g; u < je + g; u += 8) {
        int j = (u < Emax) ? u : Emax;
        int s = col[j];
        float e = asrc[s * 8 + sub] + adv;
        e = (e > 0.f) ? e : LRELU * e;
        float w = (u < je) ? __expf(e) : 0.f;
        uint4 hv = Hb8[(size_t)s * 8 + sub];
        denom += w;
        acc[0] = fmaf(w, bf2f(hv.x & 0xffffu), acc[0]);
        acc[1] = fmaf(w, bf2f(hv.x >> 16), acc[1]);
        acc[2] = fmaf(w, bf2f(hv.y & 0xffffu), acc[2]);
        acc[3] = fmaf(w, bf2f(hv.y >> 16), acc[3]);
        acc[4] = fmaf(w, bf2f(hv.z & 0xffffu), acc[4]);
        acc[5] = fmaf(w, bf2f(hv.z >> 16), acc[5]);
        acc[6] = fmaf(w, bf2f(hv.w & 0xffffu), acc[6]);
        acc[7] = fmaf(w, bf2f(hv.w >> 16), acc[7]);
    }
#pragma unroll
    for (int off = 8; off < 64; off <<= 1) {
#pragma unroll
        for (int c = 0; c < 8; ++c) acc[c] += __shfl_xor(acc[c], off, 64);
        denom += __shfl_xor(denom, off, 64);
    }
    if (lane < 8) {
        float invd = 1.f / (denom + 1e-16f);
        unsigned short pk[8];
#pragma unroll
        for (int c = 0; c < 8; ++c) {
            float v = fmaf(acc[c], invd, bias[sub * 8 + c]);
            v = (v > 0.f) ? v : expm1f(v);
            pk[c] = f2bf(v);
        }
        uint4 pv;
        pv.x = (unsigned)pk[0] | ((unsigned)pk[1] << 16);
        pv.y = (unsigned)pk[2] | ((unsigned)pk[3] << 16);
        pv.z = (unsigned)pk[4] | ((unsigned)pk[5] << 16);
        pv.w = (unsigned)pk[6] | ((unsigned)pk[7] << 16);
        *reinterpret_cast<uint4*>(&outb[(size_t)d * 64 + sub * 8]) = pv;
    }
}

__global__ __launch_bounds__(256) void k_gather2(const int* __restrict__ rowptr,
                                                 const int* __restrict__ col,
                                                 const uint4* __restrict__ Gb8,
                                                 const float* __restrict__ asrc,
                                                 const float* __restrict__ adst,
                                                 const float* __restrict__ bias,
                                                 int N, int Emax,
                                                 float* __restrict__ out) {
    int lane = threadIdx.x & 63;
    int d = (blockIdx.x << 2) + (threadIdx.x >> 6);
    if (d >= N) return;
    int g = lane >> 3;
    int sub = lane & 7;
    float adv = adst[d];
    int jb = rowptr[d], je = rowptr[d + 1];

    float acc[8] = {0.f, 0.f, 0.f, 0.f, 0.f, 0.f, 0.f, 0.f};
    float denom = 0.f;
#pragma unroll 4
    for (int u = jb + g; u < je + g; u += 8) {
        int j = (u < Emax) ? u : Emax;
        int s = col[j];
        float e = asrc[s] + adv;
        e = (e > 0.f) ? e : LRELU * e;
        float w = (u < je) ? __expf(e) : 0.f;
        uint4 hv = Gb8[(size_t)s * 8 + sub];
        denom += w;
        acc[0] = fmaf(w, bf2f(hv.x & 0xffffu), acc[0]);
        acc[1] = fmaf(w, bf2f(hv.x >> 16), acc[1]);
        acc[2] = fmaf(w, bf2f(hv.y & 0xffffu), acc[2]);
        acc[3] = fmaf(w, bf2f(hv.y >> 16), acc[3]);
        acc[4] = fmaf(w, bf2f(hv.z & 0xffffu), acc[4]);
        acc[5] = fmaf(w, bf2f(hv.z >> 16), acc[5]);
        acc[6] = fmaf(w, bf2f(hv.w & 0xffffu), acc[6]);
        acc[7] = fmaf(w, bf2f(hv.w >> 16), acc[7]);
    }
#pragma unroll
    for (int off = 8; off < 64; off <<= 1) {
#pragma unroll
        for (int c = 0; c < 8; ++c) acc[c] += __shfl_xor(acc[c], off, 64);
        denom += __shfl_xor(denom, off, 64);
    }
    float invd = 1.f / (denom + 1e-16f);
    float v[8];
#pragma unroll
    for (int c = 0; c < 8; ++c) v[c] = fmaf(acc[c], invd, bias[sub * 8 + c]);
    float m = v[0];
#pragma unroll
    for (int c = 1; c < 8; ++c) m = fmaxf(m, v[c]);
#pragma unroll
    for (int off = 1; off < 8; off <<= 1) m = fmaxf(m, __shfl_xor(m, off, 64));
    float se = 0.f;
#pragma unroll
    for (int c = 0; c < 8; ++c) se += __expf(v[c] - m);
#pragma unroll
    for (int off = 1; off < 8; off <<= 1) se += __shfl_xor(se, off, 64);
    float ls = m + __logf(se);
    if (lane < 8) {
        float4 o0, o1;
        o0.x = v[0] - ls; o0.y = v[1] - ls; o0.z = v[2] - ls; o0.w = v[3] - ls;
        o1.x = v[4] - ls; o1.y = v[5] - ls; o1.z = v[6] - ls; o1.w = v[7] - ls;
        *reinterpret_cast<float4*>(&out[(size_t)d * 64 + sub * 8]) = o0;
        *reinterpret_cast<float4*>(&out[(size_t)d * 64 + sub * 8 + 4]) = o1;
    }
}

// ---------------- launch ----------------

extern "C" void kernel_launch(void* const* d_in, const int* in_sizes, int n_in,
                              void* d_out, int out_size, void* d_ws, size_t ws_size,
                              hipStream_t stream) {
    const float* x   = (const float*)d_in[0];
    const int*   ei  = (const int*)d_in[1];
    const float* W1  = (const float*)d_in[2];
    const float* as1 = (const float*)d_in[3];
    const float* ad1 = (const float*)d_in[4];
    const float* b1  = (const float*)d_in[5];
    const float* W2  = (const float*)d_in[6];
    const float* as2 = (const float*)d_in[7];
    const float* ad2 = (const float*)d_in[8];
    const float* b2  = (const float*)d_in[9];
    float* out = (float*)d_out;

    const int N = in_sizes[0] / 256;
    const int E = in_sizes[1] / 2;
    const int* src = ei;
    const int* dst = ei + E;
    const int NB = (N + BSZ - 1) >> BSH;
    const int nchunk = (E + CH - 1) / CH;

    char* ws = (char*)d_ws;
    size_t off = 0;
    auto alloc = [&](size_t bytes) -> void* {
        void* p = ws + off;
        off = (off + bytes + 255) & ~(size_t)255;
        return p;
    };
    int*      bcnt   = (int*)alloc((size_t)NB * 4);
    int*      boff   = (int*)alloc((size_t)(NB + 1) * 4);
    int*      bcur   = (int*)alloc((size_t)NB * 4);
    int*      rowptr = (int*)alloc((size_t)(N + 1) * 4);
    int*      col    = (int*)alloc((size_t)E * 4);
    unsigned* pairs  = (unsigned*)alloc((size_t)E * 4);
    unsigned short* wt1 = (unsigned short*)alloc(64 * 256 * 2);
    unsigned short* wt2 = (unsigned short*)alloc(64 * 64 * 2);
    unsigned short* h1b = (unsigned short*)alloc((size_t)N * 64 * 2);
    float* a_s1   = (float*)alloc((size_t)N * 8 * 4);
    float* a_d1   = (float*)alloc((size_t)N * 8 * 4);
    unsigned short* h2b = (unsigned short*)alloc((size_t)N * 64 * 2);
    unsigned short* gb  = (unsigned short*)alloc((size_t)N * 64 * 2);
    float* a_s2   = (float*)alloc((size_t)N * 4);
    float* a_d2   = (float*)alloc((size_t)N * 4);
    (void)ws_size; (void)n_in; (void)out_size;

    k_cvtW<<<80, 256, 0, stream>>>(W1, W2, wt1, wt2);

    hipMemsetAsync(bcnt, 0, (size_t)NB * 4, stream);
    k_bcount<<<nchunk, 256, 0, stream>>>(dst, E, NB, bcnt);
    k_bscan<<<1, 64, 0, stream>>>(bcnt, NB, boff, bcur);
    k_binscat1<<<nchunk, 256, 0, stream>>>(src, dst, E, NB, bcur, pairs);
    k_bucket<<<NB, 256, 0, stream>>>(boff, pairs, N, rowptr, col);

    int gblk = (N + 63) / 64;
    k_gemm1m<<<gblk, 256, 0, stream>>>(x, wt1, as1, ad1, N, h1b, a_s1, a_d1);

    int gather_blocks = (N + 3) / 4;
    k_gather1<<<gather_blocks, 256, 0, stream>>>(rowptr, col, (const uint4*)h1b,
                                                 a_s1, a_d1, b1, N, E - 1, h2b);

    k_gemm2m<<<gblk, 256, 0, stream>>>(h2b, wt2, as2, ad2, N, gb, a_s2, a_d2);

    k_gather2<<<gather_blocks, 256, 0, stream>>>(rowptr, col, (const uint4*)gb,
                                                 a_s2, a_d2, b2, N, E - 1, out);
}